// Round 20
// baseline (187.697 us; speedup 1.0000x reference)
//
#include <hip/hip_runtime.h>
#include <cstdint>
#include <cstddef>

typedef __attribute__((ext_vector_type(8))) short bf16x8;
typedef __attribute__((ext_vector_type(4))) float f32x4;
typedef unsigned char uchar;

namespace {
constexpr float kScale = 0.17677669529663689f; // 32^-0.5
constexpr float kEps = 1e-6f;
constexpr float kInvC = 1.0f / 128.0f;

// tanh-form GELU as v*sigmoid(2u) (exact-form, bf16 paths).
__device__ __forceinline__ float gelu_fast(float v) {
  float t1 = fmaf(0.044715f * v, v, 1.0f);
  float x = v * t1 * -1.5957691216057308f;
  float e = __expf(x);
  return v * __builtin_amdgcn_rcpf(1.0f + e);
}
// sigmoid-form GELU v*sigma(1.702v): |err|<=0.003 for |v|<1 — below fp8 noise.
__device__ __forceinline__ float gelu_sig(float v) {
  float e = __expf(-1.702f * v);
  return v * __builtin_amdgcn_rcpf(1.0f + e);
}
__device__ __forceinline__ ushort f2bf(float f) {
  uint32_t u = __builtin_bit_cast(uint32_t, f);
  u += 0x7FFFu + ((u >> 16) & 1u);
  return (ushort)(u >> 16);
}
__device__ __forceinline__ float bf2f(ushort u) {
  return __builtin_bit_cast(float, (uint32_t)u << 16);
}
// async global->LDS, 16B per lane. LDS dest is wave-uniform base + lane*16.
__device__ __forceinline__ void gl16(const void* g, void* l) {
  __builtin_amdgcn_global_load_lds(
      (const __attribute__((address_space(1))) void*)g,
      (__attribute__((address_space(3))) void*)l, 16, 0, 0);
}
// window-token -> natural-token row map (reverse shift + reverse partition)
__device__ __forceinline__ int map_row(int t) {
  int win = t / 49, nn = t - win * 49;
  int bb = win >> 6, wi = win & 63;
  int whi = wi >> 3, wwi = wi & 7;
  int r7 = nn / 7, c7 = nn - r7 * 7;
  int hs = whi * 7 + r7 + 3; if (hs >= 56) hs -= 56;
  int wsd = wwi * 7 + c7 + 3; if (wsd >= 56) wsd -= 56;
  return bb * 3136 + hs * 56 + wsd;
}
} // namespace

// ---------------------------------------------------------------------------
// K0: convert weights: qkvT/w1T bf16 [N][K]; w2T8 fp8 [128][512]; projT bf16.
// ---------------------------------------------------------------------------
__global__ __launch_bounds__(256) void k_prep(
    const float* __restrict__ qkv_w, const float* __restrict__ w1,
    const float* __restrict__ w2, const float* __restrict__ pw,
    ushort* __restrict__ qkvT, ushort* __restrict__ w1T,
    uchar* __restrict__ w2T8, ushort* __restrict__ projT) {
  int i = blockIdx.x * 256 + threadIdx.x;
  if (i < 49152) {
    int n = i >> 7, k = i & 127;
    qkvT[i] = f2bf(qkv_w[k * 384 + n]);
  } else if (i < 114688) {
    int j = i - 49152;
    int n = j >> 7, k = j & 127;
    w1T[j] = f2bf(w1[k * 512 + n]);
  } else if (i < 147456) {
    int j = i - 114688;            // 32768 k-pairs
    int n = j >> 8, k2 = (j & 255) << 1;
    int u = __builtin_amdgcn_cvt_pk_fp8_f32(w2[(size_t)k2 * 128 + n],
                                            w2[(size_t)(k2 + 1) * 128 + n], 0,
                                            false);
    w2T8[n * 512 + k2] = (uchar)u;
    w2T8[n * 512 + k2 + 1] = (uchar)(u >> 8);
  } else if (i < 163840) {
    int j = i - 147456;
    int n = j >> 7, k = j & 127;
    projT[j] = f2bf(pw[k * 128 + n]);
  }
}

// ---------------------------------------------------------------------------
// K0b: precompute bias+mask table TB[type(4)][head(4)][j(64)][i(64)] f32.
// ---------------------------------------------------------------------------
__global__ __launch_bounds__(256) void k_prep2(
    const float* __restrict__ rpb, float* __restrict__ TB) {
  int e = blockIdx.x * 256 + threadIdx.x;  // < 65536
  int i = e & 63, j = (e >> 6) & 63, h = (e >> 12) & 3, type = e >> 14;
  float v = 0.f;
  if (i < 49 && j < 49) {
    int ri = i / 7, ci = i - ri * 7, rj = j / 7, cj = j - rj * 7;
    int ridx = (ri - rj + 6) * 13 + (ci - cj + 6);
    float bias = rpb[ridx * 4 + h];
    int th = type >> 1, tw = type & 1;
    int labi = (th ? ((ri < 4) ? 1 : 2) : 0) * 3 + (tw ? ((ci < 4) ? 1 : 2) : 0);
    int labj = (th ? ((rj < 4) ? 1 : 2) : 0) * 3 + (tw ? ((cj < 4) ? 1 : 2) : 0);
    v = bias + ((labi != labj) ? -100.f : 0.f);
  }
  TB[e] = v;
}

// ---------------------------------------------------------------------------
// K-QKVF (M=64 tile): fused LN1 + QKV GEMM.
// A-tile produced in-kernel: read x rows (gathered), LN1 in registers,
// swizzled ds_write matching the (chunk ^ row&7) read pattern.
// ---------------------------------------------------------------------------
__global__ __launch_bounds__(256) void k_qkvf(
    const float* __restrict__ x, const float* __restrict__ g1,
    const float* __restrict__ b1, const ushort* __restrict__ BT,
    const float* __restrict__ bias, ushort* __restrict__ C) {
  __shared__ ushort sbuf[12288];  // A 4096 | B 8192 (ushorts)
  __shared__ int mapr[64];
  int tid = threadIdx.x;
  int nBase = blockIdx.x << 7;
  int mBase = blockIdx.y << 6;
  if (tid < 64) mapr[tid] = map_row(mBase + tid);
  int lane = tid & 63, wid = tid >> 6;
  int li = lane & 15, g = lane >> 4;
  int wr = (wid >> 1) << 5, wc = (wid & 1) << 6;
  int swz = (li & 7) << 3;
  int r = tid >> 2, q = tid & 3;   // 4 threads per A-row
  __syncthreads();                 // mapr visible
  const float* xr = x + (size_t)mapr[r] * 128;
  // LN1 stats for row r (each thread covers 32 cols; reduce over quartet)
  float s = 0.f, sq = 0.f;
#pragma unroll
  for (int j = 0; j < 8; ++j) {
    float4 v = *(const float4*)(xr + q * 32 + j * 4);
    s += v.x + v.y + v.z + v.w;
    sq += v.x * v.x + v.y * v.y + v.z * v.z + v.w * v.w;
  }
  s += __shfl_xor(s, 1); s += __shfl_xor(s, 2);
  sq += __shfl_xor(sq, 1); sq += __shfl_xor(sq, 2);
  float mu = s * kInvC;
  float rs = rsqrtf(sq * kInvC - mu * mu + kEps);
  f32x4 acc[2][4] = {};
#pragma unroll
  for (int h = 0; h < 2; ++h) {
    int ks = h << 6;
    // stage B via gl16
#pragma unroll
    for (int l = 0; l < 4; ++l) {
      int c = l * 256 + tid;
      int row = c >> 3;
      int k8 = ((c & 7) ^ (row & 7)) << 3;
      gl16(BT + (size_t)(nBase + row) * 128 + ks + k8,
           sbuf + 4096 + (l * 256 + wid * 64) * 8);
    }
    // stage A: LN'd bf16, swizzled ds_write (16 cols/thread)
#pragma unroll
    for (int c2 = 0; c2 < 2; ++c2) {
      int cc = ks + q * 16 + c2 * 8;
      float4 v0 = *(const float4*)(xr + cc);
      float4 v1 = *(const float4*)(xr + cc + 4);
      float4 gg0 = *(const float4*)(g1 + cc);
      float4 gg1 = *(const float4*)(g1 + cc + 4);
      float4 bb0 = *(const float4*)(b1 + cc);
      float4 bb1 = *(const float4*)(b1 + cc + 4);
      bf16x8 pk;
      pk[0] = (short)f2bf((v0.x - mu) * rs * gg0.x + bb0.x);
      pk[1] = (short)f2bf((v0.y - mu) * rs * gg0.y + bb0.y);
      pk[2] = (short)f2bf((v0.z - mu) * rs * gg0.z + bb0.z);
      pk[3] = (short)f2bf((v0.w - mu) * rs * gg0.w + bb0.w);
      pk[4] = (short)f2bf((v1.x - mu) * rs * gg1.x + bb1.x);
      pk[5] = (short)f2bf((v1.y - mu) * rs * gg1.y + bb1.y);
      pk[6] = (short)f2bf((v1.z - mu) * rs * gg1.z + bb1.z);
      pk[7] = (short)f2bf((v1.w - mu) * rs * gg1.w + bb1.w);
      int ch = (cc - ks) >> 3;  // 0..7 within half
      *(bf16x8*)(sbuf + r * 64 + ((ch ^ (r & 7)) << 3)) = pk;
    }
    __syncthreads();
#pragma unroll
    for (int ksub = 0; ksub < 64; ksub += 32) {
      int kloc = ksub + g * 8;
      bf16x8 af[2], bfr[4];
#pragma unroll
      for (int m = 0; m < 2; ++m)
        af[m] = *(const bf16x8*)(sbuf + (wr + m * 16 + li) * 64 + (kloc ^ swz));
#pragma unroll
      for (int n = 0; n < 4; ++n)
        bfr[n] = *(const bf16x8*)(sbuf + 4096 + (wc + n * 16 + li) * 64 +
                                  (kloc ^ swz));
#pragma unroll
      for (int m = 0; m < 2; ++m)
#pragma unroll
        for (int n = 0; n < 4; ++n)
          acc[m][n] = __builtin_amdgcn_mfma_f32_16x16x32_bf16(
              af[m], bfr[n], acc[m][n], 0, 0, 0);
    }
    __syncthreads();
  }
  // Cs: 64 rows x 128 cols, row stride 136 ushorts (17.4KB overlay)
#pragma unroll
  for (int n = 0; n < 4; ++n) {
    float bv = bias[nBase + wc + n * 16 + li];
    int col = wc + n * 16 + li;
#pragma unroll
    for (int m = 0; m < 2; ++m) {
      int rb = wr + m * 16 + (g << 2);
#pragma unroll
      for (int rr = 0; rr < 4; ++rr)
        sbuf[(rb + rr) * 136 + col] = f2bf(acc[m][n][rr] + bv);
    }
  }
  __syncthreads();
#pragma unroll
  for (int it = 0; it < 4; ++it) {
    int ch = tid + it * 256;  // 1024 chunks of 8
    int row = ch >> 4, c8 = (ch & 15) << 3;
    *(bf16x8*)(C + (size_t)(mBase + row) * 384 + nBase + c8) =
        *(const bf16x8*)(sbuf + row * 136 + c8);
  }
}

// ---------------------------------------------------------------------------
// K-MLP1 (M=64 tile): hb8[64, 128-chunk] = fp8(gelu_sig(wp@w1T^T + b1)).
// Padded Cs8 stride (144 B) -> conflict-free byte writes.
// ---------------------------------------------------------------------------
__global__ __launch_bounds__(256) void k_mlp1(
    const ushort* __restrict__ A, const ushort* __restrict__ BT,
    const float* __restrict__ bias, uchar* __restrict__ C8) {
  __shared__ ushort sbuf[12288];
  int tid = threadIdx.x;
  int nBase = blockIdx.x << 7;
  int mBase = blockIdx.y << 6;
  int lane = tid & 63, wid = tid >> 6;
  int li = lane & 15, g = lane >> 4;
  int wr = (wid >> 1) << 5, wc = (wid & 1) << 6;
  int swz = (li & 7) << 3;
  f32x4 acc[2][4] = {};
  for (int ks = 0; ks < 128; ks += 64) {
#pragma unroll
    for (int l = 0; l < 2; ++l) {
      int c = l * 256 + tid;
      int row = c >> 3;
      int k8 = ((c & 7) ^ (row & 7)) << 3;
      gl16(A + (size_t)(mBase + row) * 128 + ks + k8,
           sbuf + (l * 256 + wid * 64) * 8);
    }
#pragma unroll
    for (int l = 0; l < 4; ++l) {
      int c = l * 256 + tid;
      int row = c >> 3;
      int k8 = ((c & 7) ^ (row & 7)) << 3;
      gl16(BT + (size_t)(nBase + row) * 128 + ks + k8,
           sbuf + 4096 + (l * 256 + wid * 64) * 8);
    }
    __syncthreads();
#pragma unroll
    for (int ksub = 0; ksub < 64; ksub += 32) {
      int kloc = ksub + g * 8;
      bf16x8 af[2], bfr[4];
#pragma unroll
      for (int m = 0; m < 2; ++m)
        af[m] = *(const bf16x8*)(sbuf + (wr + m * 16 + li) * 64 + (kloc ^ swz));
#pragma unroll
      for (int n = 0; n < 4; ++n)
        bfr[n] = *(const bf16x8*)(sbuf + 4096 + (wc + n * 16 + li) * 64 +
                                  (kloc ^ swz));
#pragma unroll
      for (int m = 0; m < 2; ++m)
#pragma unroll
        for (int n = 0; n < 4; ++n)
          acc[m][n] = __builtin_amdgcn_mfma_f32_16x16x32_bf16(
              af[m], bfr[n], acc[m][n], 0, 0, 0);
    }
    __syncthreads();
  }
  // Cs8: 64 rows x 128 B, row stride 144 B (9.2KB overlay)
  uchar* Cs8 = (uchar*)sbuf;
#pragma unroll
  for (int n = 0; n < 4; ++n) {
    float bv = bias[nBase + wc + n * 16 + li];
    int col = wc + n * 16 + li;
#pragma unroll
    for (int m = 0; m < 2; ++m) {
      int rb = wr + m * 16 + (g << 2);
      float v0 = gelu_sig(acc[m][n][0] + bv);
      float v1 = gelu_sig(acc[m][n][1] + bv);
      float v2 = gelu_sig(acc[m][n][2] + bv);
      float v3 = gelu_sig(acc[m][n][3] + bv);
      int u01 = __builtin_amdgcn_cvt_pk_fp8_f32(v0, v1, 0, false);
      int u23 = __builtin_amdgcn_cvt_pk_fp8_f32(v2, v3, 0, false);
      Cs8[(rb + 0) * 144 + col] = (uchar)u01;
      Cs8[(rb + 1) * 144 + col] = (uchar)(u01 >> 8);
      Cs8[(rb + 2) * 144 + col] = (uchar)u23;
      Cs8[(rb + 3) * 144 + col] = (uchar)(u23 >> 8);
    }
  }
  __syncthreads();
#pragma unroll
  for (int it = 0; it < 2; ++it) {
    int ch = tid + it * 256;  // 512 chunks of 16B
    int row = ch >> 3, c16 = (ch & 7) << 4;
    *(bf16x8*)(C8 + (size_t)(mBase + row) * 512 + nBase + c16) =
        *(const bf16x8*)(Cs8 + row * 144 + c16);
  }
}

// ---------------------------------------------------------------------------
// K-MLP2 (M=64 tile, fp8): out[map(row)] = res_w + hb8 @ w2T8^T + b2.
// ---------------------------------------------------------------------------
__global__ __launch_bounds__(256) void k_mlp2(
    const uchar* __restrict__ A8, const uchar* __restrict__ BT8,
    const float* __restrict__ bias, const ushort* __restrict__ resw,
    float* __restrict__ out) {
  __shared__ uchar sbuf[32768];  // tiles: A 8KB | B 16KB; then f32 out 32KB
  __shared__ int mapr[64];
  int tid = threadIdx.x;
  int mBase = blockIdx.x << 6;
  if (tid < 64) mapr[tid] = map_row(mBase + tid);
  int lane = tid & 63, wid = tid >> 6;
  int li = lane & 15, g = lane >> 4;
  int wr = (wid >> 1) << 5, wc = (wid & 1) << 6;
  f32x4 acc[2][4] = {};
  for (int kb = 0; kb < 512; kb += 128) {
#pragma unroll
    for (int l = 0; l < 2; ++l) {  // A: 64 rows x 128B
      int c = l * 256 + tid;
      int row = c >> 3;
      int ch = (c & 7) ^ (row & 7);
      gl16(A8 + (size_t)(mBase + row) * 512 + kb + (ch << 4),
           sbuf + (l * 256 + wid * 64) * 16);
    }
#pragma unroll
    for (int l = 0; l < 4; ++l) {  // B: 128 rows x 128B
      int c = l * 256 + tid;
      int row = c >> 3;
      int ch = (c & 7) ^ (row & 7);
      gl16(BT8 + (size_t)row * 512 + kb + (ch << 4),
           sbuf + 8192 + (l * 256 + wid * 64) * 16);
    }
    __syncthreads();
#pragma unroll
    for (int ks = 0; ks < 4; ++ks) {
      int off = ks * 32 + g * 8;
      long long af[2], bfr[4];
#pragma unroll
      for (int m = 0; m < 2; ++m) {
        int r = wr + m * 16 + li;
        af[m] = *(const long long*)(sbuf + r * 128 + (off ^ ((r & 7) << 4)));
      }
#pragma unroll
      for (int n = 0; n < 4; ++n) {
        int rb = wc + n * 16 + li;
        bfr[n] = *(const long long*)(sbuf + 8192 + rb * 128 +
                                     (off ^ ((rb & 7) << 4)));
      }
#pragma unroll
      for (int m = 0; m < 2; ++m)
#pragma unroll
        for (int n = 0; n < 4; ++n)
          acc[m][n] = __builtin_amdgcn_mfma_f32_16x16x32_fp8_fp8(
              af[m], bfr[n], acc[m][n], 0, 0, 0);
    }
    __syncthreads();
  }
  float (*outs)[128] = (float(*)[128])sbuf;  // 32 KB f32 overlay
#pragma unroll
  for (int n = 0; n < 4; ++n) {
    int cg = wc + n * 16 + li;
    float bv = bias[cg];
#pragma unroll
    for (int m = 0; m < 2; ++m) {
      int rb = wr + m * 16 + (g << 2);
#pragma unroll
      for (int r = 0; r < 4; ++r) {
        float rv = bf2f(resw[(size_t)(mBase + rb + r) * 128 + cg]);
        outs[rb + r][cg] = rv + acc[m][n][r] + bv;
      }
    }
  }
  __syncthreads();
#pragma unroll
  for (int it = 0; it < 8; ++it) {
    int ch = tid + it * 256;  // 2048 float4 chunks
    int row = ch >> 5, c4 = (ch & 31) << 2;
    *(float4*)(out + (size_t)mapr[row] * 128 + c4) =
        *(const float4*)&outs[row][c4];
  }
}

// ---------------------------------------------------------------------------
// K-PGEMM (M=64 tile): proj GEMM + bias + row-LN(proj_ln) + GELU
//   + residual(x gather) + LN2 -> res_w (bf16) + wp (LN2 bf16).
// ---------------------------------------------------------------------------
__global__ __launch_bounds__(256) void k_pgemm(
    const ushort* __restrict__ A, const ushort* __restrict__ BT,
    const float* __restrict__ pb, const float* __restrict__ lg,
    const float* __restrict__ lb, const float* __restrict__ x,
    const float* __restrict__ g2, const float* __restrict__ b2n,
    ushort* __restrict__ resw, ushort* __restrict__ wp) {
  __shared__ ushort sbuf[16384];  // 32 KB: tiles (24KB), then Cr|Cw overlay
  __shared__ float red[4][64][2];
  __shared__ int mapr[64];
  int tid = threadIdx.x;
  int mBase = blockIdx.x << 6;
  if (tid < 64) mapr[tid] = map_row(mBase + tid);
  int lane = tid & 63, wid = tid >> 6;
  int li = lane & 15, g = lane >> 4;
  int wr = (wid >> 1) << 5, wc = (wid & 1) << 6;
  int swz = (li & 7) << 3;
  f32x4 acc[2][4] = {};
  for (int ks = 0; ks < 128; ks += 64) {
#pragma unroll
    for (int l = 0; l < 2; ++l) {
      int c = l * 256 + tid;
      int row = c >> 3;
      int k8 = ((c & 7) ^ (row & 7)) << 3;
      gl16(A + (size_t)(mBase + row) * 128 + ks + k8,
           sbuf + (l * 256 + wid * 64) * 8);
    }
#pragma unroll
    for (int l = 0; l < 4; ++l) {
      int c = l * 256 + tid;
      int row = c >> 3;
      int k8 = ((c & 7) ^ (row & 7)) << 3;
      gl16(BT + (size_t)row * 128 + ks + k8,
           sbuf + 4096 + (l * 256 + wid * 64) * 8);
    }
    __syncthreads();
#pragma unroll
    for (int ksub = 0; ksub < 64; ksub += 32) {
      int kloc = ksub + g * 8;
      bf16x8 af[2], bfr[4];
#pragma unroll
      for (int m = 0; m < 2; ++m)
        af[m] = *(const bf16x8*)(sbuf + (wr + m * 16 + li) * 64 + (kloc ^ swz));
#pragma unroll
      for (int n = 0; n < 4; ++n)
        bfr[n] = *(const bf16x8*)(sbuf + 4096 + (wc + n * 16 + li) * 64 +
                                  (kloc ^ swz));
#pragma unroll
      for (int m = 0; m < 2; ++m)
#pragma unroll
        for (int n = 0; n < 4; ++n)
          acc[m][n] = __builtin_amdgcn_mfma_f32_16x16x32_bf16(
              af[m], bfr[n], acc[m][n], 0, 0, 0);
    }
    __syncthreads();
  }
  float pbv[4], lgv[4], lbv[4], g2v[4], b2v[4];
#pragma unroll
  for (int n = 0; n < 4; ++n) {
    int cg = wc + n * 16 + li;
    pbv[n] = pb[cg]; lgv[n] = lg[cg]; lbv[n] = lb[cg];
    g2v[n] = g2[cg]; b2v[n] = b2n[cg];
  }
  // pass 1: proj-LN stats (wave covers 64 cols; partner wid^1 has other 64)
  float ps[2][4], psq[2][4];
#pragma unroll
  for (int m = 0; m < 2; ++m)
#pragma unroll
    for (int r = 0; r < 4; ++r) {
      float s = 0.f, q = 0.f;
#pragma unroll
      for (int n = 0; n < 4; ++n) {
        float v = acc[m][n][r] + pbv[n];
        s += v; q += v * v;
      }
#pragma unroll
      for (int off = 1; off < 16; off <<= 1) {
        s += __shfl_xor(s, off);
        q += __shfl_xor(q, off);
      }
      ps[m][r] = s; psq[m][r] = q;
    }
  if (li == 0) {
#pragma unroll
    for (int m = 0; m < 2; ++m)
#pragma unroll
      for (int r = 0; r < 4; ++r) {
        int rl = wr + m * 16 + (g << 2) + r;
        red[wid][rl][0] = ps[m][r];
        red[wid][rl][1] = psq[m][r];
      }
  }
  __syncthreads();
  float mu1[2][4], rs1[2][4];
#pragma unroll
  for (int m = 0; m < 2; ++m)
#pragma unroll
    for (int r = 0; r < 4; ++r) {
      int rl = wr + m * 16 + (g << 2) + r;
      float s = ps[m][r] + red[wid ^ 1][rl][0];
      float q = psq[m][r] + red[wid ^ 1][rl][1];
      mu1[m][r] = s * kInvC;
      rs1[m][r] = rsqrtf(q * kInvC - mu1[m][r] * mu1[m][r] + kEps);
    }
  __syncthreads();  // red free for round 2
  // transform: acc <- res = gelu(projLN(y)) + x[map(row)]
#pragma unroll
  for (int m = 0; m < 2; ++m)
#pragma unroll
    for (int r = 0; r < 4; ++r) {
      int rowl = wr + m * 16 + (g << 2) + r;
      size_t xb = (size_t)mapr[rowl] * 128 + wc + li;
#pragma unroll
      for (int n = 0; n < 4; ++n) {
        float y = (acc[m][n][r] + pbv[n] - mu1[m][r]) * rs1[m][r] * lgv[n] +
                  lbv[n];
        acc[m][n][r] = gelu_fast(y) + x[xb + n * 16];
      }
    }
  // pass 2: LN2 stats on res
#pragma unroll
  for (int m = 0; m < 2; ++m)
#pragma unroll
    for (int r = 0; r < 4; ++r) {
      float s = 0.f, q = 0.f;
#pragma unroll
      for (int n = 0; n < 4; ++n) {
        float v = acc[m][n][r];
        s += v; q += v * v;
      }
#pragma unroll
      for (int off = 1; off < 16; off <<= 1) {
        s += __shfl_xor(s, off);
        q += __shfl_xor(q, off);
      }
      ps[m][r] = s; psq[m][r] = q;
    }
  if (li == 0) {
#pragma unroll
    for (int m = 0; m < 2; ++m)
#pragma unroll
      for (int r = 0; r < 4; ++r) {
        int rl = wr + m * 16 + (g << 2) + r;
        red[wid][rl][0] = ps[m][r];
        red[wid][rl][1] = psq[m][r];
      }
  }
  __syncthreads();
  ushort (*Cr)[128] = (ushort(*)[128])sbuf;            // res bf16 (16KB)
  ushort (*Cw)[128] = (ushort(*)[128])(sbuf + 8192);   // LN2 bf16 (16KB)
#pragma unroll
  for (int m = 0; m < 2; ++m)
#pragma unroll
    for (int r = 0; r < 4; ++r) {
      int rl = wr + m * 16 + (g << 2) + r;
      float s = ps[m][r] + red[wid ^ 1][rl][0];
      float q = psq[m][r] + red[wid ^ 1][rl][1];
      float mu = s * kInvC;
      float rs = rsqrtf(q * kInvC - mu * mu + kEps);
#pragma unroll
      for (int n = 0; n < 4; ++n) {
        int col = wc + n * 16 + li;
        float rv = acc[m][n][r];
        Cr[rl][col] = f2bf(rv);
        Cw[rl][col] = f2bf((rv - mu) * rs * g2v[n] + b2v[n]);
      }
    }
  __syncthreads();
#pragma unroll
  for (int it = 0; it < 4; ++it) {
    int ch = tid + it * 256;  // 1024 chunks of 8
    int row = ch >> 4, c8 = (ch & 15) << 3;
    *(bf16x8*)(resw + (size_t)(mBase + row) * 128 + c8) =
        *(const bf16x8*)&Cr[row][c8];
    *(bf16x8*)(wp + (size_t)(mBase + row) * 128 + c8) =
        *(const bf16x8*)&Cw[row][c8];
  }
}

// ---------------------------------------------------------------------------
// K3: MFMA attention. 1 block = 1 window, 1 wave = 1 head. bf16 P/V.
// Stride-68 LDS (51KB -> 3 blocks/CU); max-free double softmax.
// ---------------------------------------------------------------------------
__global__ __launch_bounds__(256) void k_attn(
    const ushort* __restrict__ qkv, const float* __restrict__ TB,
    ushort* __restrict__ ob) {
  __shared__ ushort Pl[4][64][68];
  __shared__ ushort Vt[4][32][68];
  int tid = threadIdx.x;
  int lane = tid & 63, h = tid >> 6;
  int li = lane & 15, g = lane >> 4;
  int win = blockIdx.x;
  int wi = win & 63;
  int type = (((wi >> 3) == 7) ? 2 : 0) | (((wi & 7) == 7) ? 1 : 0);

  const ushort* qbase = qkv + (size_t)win * 49 * 384 + h * 32 + g * 8;
  bf16x8 kf[4], qf[4];
#pragma unroll
  for (int m = 0; m < 4; ++m) {
    kf[m] = *(const bf16x8*)(qbase + (size_t)(m * 16 + li) * 384 + 128);
    qf[m] = *(const bf16x8*)(qbase + (size_t)(m * 16 + li) * 384);
  }
  f32x4 zero = {0.f, 0.f, 0.f, 0.f};
  f32x4 st[4][4];
#pragma unroll
  for (int m = 0; m < 4; ++m)
#pragma unroll
    for (int n = 0; n < 4; ++n)
      st[m][n] = __builtin_amdgcn_mfma_f32_16x16x32_bf16(kf[m], qf[n], zero, 0, 0, 0);

  if (lane < 49) {
#pragma unroll
    for (int dc = 0; dc < 4; ++dc) {
      bf16x8 vv = *(const bf16x8*)(qkv + ((size_t)win * 49 + lane) * 384 + 256 +
                                   h * 32 + dc * 8);
#pragma unroll
      for (int t = 0; t < 8; ++t) Vt[h][dc * 8 + t][lane] = (ushort)vv[t];
    }
  } else {
#pragma unroll
    for (int d = 0; d < 32; ++d) Vt[h][d][lane] = 0;
  }

  const float* tb = TB + ((size_t)(type * 4 + h) << 12);
#pragma unroll
  for (int n = 0; n < 4; ++n) {
    int icol = n * 16 + li;
    float sv[3][4];
#pragma unroll
    for (int m = 0; m < 3; ++m)
#pragma unroll
      for (int r = 0; r < 4; ++r)
        sv[m][r] = st[m][n][r] * kScale + tb[(m * 16 + g * 4 + r) * 64 + icol];
    float sv3 = (g == 0) ? (st[3][n][0] * kScale + tb[48 * 64 + icol]) : -1e30f;
    // softmax pass 1 (max-free: scores bounded; mask exp underflows to 0)
    float e[3][4], e3 = __expf(sv3);
    float sum = e3;
#pragma unroll
    for (int m = 0; m < 3; ++m)
#pragma unroll
      for (int r = 0; r < 4; ++r) { e[m][r] = __expf(sv[m][r]); sum += e[m][r]; }
    sum += __shfl_xor(sum, 16);
    sum += __shfl_xor(sum, 32);
    float inv = 1.f / sum;
    // softmax pass 2 (inputs in [0,1]; max-free)
    float e2[3][4];
    float e23 = (g == 0) ? __expf(e3 * inv) : 0.f;
    float sum2 = e23;
#pragma unroll
    for (int m = 0; m < 3; ++m)
#pragma unroll
      for (int r = 0; r < 4; ++r) { e2[m][r] = __expf(e[m][r] * inv); sum2 += e2[m][r]; }
    sum2 += __shfl_xor(sum2, 16);
    sum2 += __shfl_xor(sum2, 32);
    float inv2 = 1.f / sum2;
#pragma unroll
    for (int m = 0; m < 3; ++m) {
      uint u0 = (uint)f2bf(e2[m][0] * inv2) | ((uint)f2bf(e2[m][1] * inv2) << 16);
      uint u1 = (uint)f2bf(e2[m][2] * inv2) | ((uint)f2bf(e2[m][3] * inv2) << 16);
      *(uint*)&Pl[h][icol][m * 16 + g * 4]     = u0;
      *(uint*)&Pl[h][icol][m * 16 + g * 4 + 2] = u1;
    }
    uint u3 = (g == 0) ? (uint)f2bf(e23 * inv2) : 0u;
    *(uint*)&Pl[h][icol][48 + g * 4]     = u3;
    *(uint*)&Pl[h][icol][48 + g * 4 + 2] = 0u;
  }
  __syncthreads();

  f32x4 oacc[4][2] = {};
#pragma unroll
  for (int ks = 0; ks < 2; ++ks) {
    int kloc = ks * 32 + g * 8;
    bf16x8 bf0 = *(const bf16x8*)&Vt[h][li][kloc];
    bf16x8 bf1 = *(const bf16x8*)&Vt[h][16 + li][kloc];
#pragma unroll
    for (int mi = 0; mi < 4; ++mi) {
      bf16x8 af = *(const bf16x8*)&Pl[h][mi * 16 + li][kloc];
      oacc[mi][0] = __builtin_amdgcn_mfma_f32_16x16x32_bf16(af, bf0, oacc[mi][0], 0, 0, 0);
      oacc[mi][1] = __builtin_amdgcn_mfma_f32_16x16x32_bf16(af, bf1, oacc[mi][1], 0, 0, 0);
    }
  }
  // stage O (49 x 32 per head) into Pl[h] (stride 40), then wide stores
  ushort* OlH = &Pl[h][0][0];
#pragma unroll
  for (int mi = 0; mi < 4; ++mi)
#pragma unroll
    for (int r = 0; r < 4; ++r) {
      int i = mi * 16 + g * 4 + r;
      if (mi < 3 || (g == 0 && r == 0)) {
        OlH[i * 40 + li]      = f2bf(oacc[mi][0][r]);
        OlH[i * 40 + 16 + li] = f2bf(oacc[mi][1][r]);
      }
    }
  __syncthreads();
  ushort* obase = ob + (size_t)win * 49 * 128;
#pragma unroll
  for (int it = 0; it < 4; ++it) {
    int chunk = tid + it * 256;  // 784 chunks of 8 ushorts
    if (chunk < 784) {
      int row = chunk >> 4, c8 = (chunk & 15) << 3;
      int h2 = c8 >> 5, d8 = c8 & 31;
      bf16x8 v = *(const bf16x8*)(&Pl[h2][0][0] + row * 40 + d8);
      *(bf16x8*)(obase + (size_t)row * 128 + c8) = v;
    }
  }
}

extern "C" void kernel_launch(void* const* d_in, const int* in_sizes, int n_in,
                              void* d_out, int out_size, void* d_ws,
                              size_t ws_size, hipStream_t stream) {
  (void)in_sizes; (void)n_in; (void)out_size; (void)ws_size;
  const float* x      = (const float*)d_in[0];
  const float* qkv_w  = (const float*)d_in[1];
  const float* qkv_b  = (const float*)d_in[2];
  const float* proj_w = (const float*)d_in[3];
  const float* proj_b = (const float*)d_in[4];
  const float* plg    = (const float*)d_in[5];
  const float* plb    = (const float*)d_in[6];
  const float* rpb    = (const float*)d_in[7];
  const float* n1g    = (const float*)d_in[8];
  const float* n1b    = (const float*)d_in[9];
  const float* n2g    = (const float*)d_in[10];
  const float* n2b    = (const float*)d_in[11];
  const float* w1     = (const float*)d_in[12];
  const float* b1     = (const float*)d_in[13];
  const float* w2     = (const float*)d_in[14];
  const float* b2     = (const float*)d_in[15];
  float* out = (float*)d_out;

  // ws layout, ~180 MB
  ushort* wp   = (ushort*)d_ws;                         // 100352*128 bf16
  ushort* qkvb = wp + (size_t)100352 * 128;             // 100352*384 bf16
  ushort* obb  = qkvb + (size_t)100352 * 384;           // 100352*128 bf16
  uchar*  hb8  = (uchar*)(obb + (size_t)100352 * 128);  // 100352*512 fp8
  ushort* qkvT = (ushort*)(hb8 + (size_t)100352 * 512); // 384*128 bf16
  ushort* w1T  = qkvT + 384 * 128;                      // 512*128 bf16
  uchar*  w2T8 = (uchar*)(w1T + 512 * 128);             // 128*512 fp8
  ushort* pT   = (ushort*)(w2T8 + 128 * 512);           // 128*128 bf16
  float*  TB   = (float*)(pT + 128 * 128);              // 4*4*64*64 f32
  ushort* resw = qkvb;  // alias: qkvb dead after k_attn

  k_prep<<<640, 256, 0, stream>>>(qkv_w, w1, w2, proj_w, qkvT, w1T, w2T8, pT);
  k_prep2<<<256, 256, 0, stream>>>(rpb, TB);
  k_qkvf<<<dim3(3, 1568), 256, 0, stream>>>(x, n1g, n1b, qkvT, qkv_b, qkvb);
  k_attn<<<2048, 256, 0, stream>>>(qkvb, TB, obb);
  k_pgemm<<<1568, 256, 0, stream>>>(obb, pT, proj_b, plg, plb, x, n2g, n2b,
                                    resw, wp);
  k_mlp1<<<dim3(4, 1568), 256, 0, stream>>>(wp, w1T, b1, hb8);
  k_mlp2<<<1568, 256, 0, stream>>>(hb8, w2T8, b2, resw, out);
}

// Round 21
// 168.731 us; speedup vs baseline: 1.1124x; 1.1124x over previous
//
#include <hip/hip_runtime.h>
#include <cstdint>
#include <cstddef>

typedef __attribute__((ext_vector_type(8))) short bf16x8;
typedef __attribute__((ext_vector_type(4))) float f32x4;
typedef unsigned char uchar;

namespace {
constexpr float kScale = 0.17677669529663689f; // 32^-0.5
constexpr float kEps = 1e-6f;
constexpr float kInvC = 1.0f / 128.0f;

// tanh-form GELU as v*sigmoid(2u) (exact-form, bf16 paths).
__device__ __forceinline__ float gelu_fast(float v) {
  float t1 = fmaf(0.044715f * v, v, 1.0f);
  float x = v * t1 * -1.5957691216057308f;
  float e = __expf(x);
  return v * __builtin_amdgcn_rcpf(1.0f + e);
}
// sigmoid-form GELU v*sigma(1.702v): |err|<=0.003 for |v|<1 — below fp8 noise.
__device__ __forceinline__ float gelu_sig(float v) {
  float e = __expf(-1.702f * v);
  return v * __builtin_amdgcn_rcpf(1.0f + e);
}
__device__ __forceinline__ ushort f2bf(float f) {
  uint32_t u = __builtin_bit_cast(uint32_t, f);
  u += 0x7FFFu + ((u >> 16) & 1u);
  return (ushort)(u >> 16);
}
__device__ __forceinline__ float bf2f(ushort u) {
  return __builtin_bit_cast(float, (uint32_t)u << 16);
}
// async global->LDS, 16B per lane. LDS dest is wave-uniform base + lane*16.
__device__ __forceinline__ void gl16(const void* g, void* l) {
  __builtin_amdgcn_global_load_lds(
      (const __attribute__((address_space(1))) void*)g,
      (__attribute__((address_space(3))) void*)l, 16, 0, 0);
}
// window-token -> natural-token row map (reverse shift + reverse partition)
__device__ __forceinline__ int map_row(int t) {
  int win = t / 49, nn = t - win * 49;
  int bb = win >> 6, wi = win & 63;
  int whi = wi >> 3, wwi = wi & 7;
  int r7 = nn / 7, c7 = nn - r7 * 7;
  int hs = whi * 7 + r7 + 3; if (hs >= 56) hs -= 56;
  int wsd = wwi * 7 + c7 + 3; if (wsd >= 56) wsd -= 56;
  return bb * 3136 + hs * 56 + wsd;
}
} // namespace

// ---------------------------------------------------------------------------
// K0: convert weights: qkvT/w1T bf16 [N][K]; w2T8 fp8 [128][512]; projT bf16.
// ---------------------------------------------------------------------------
__global__ __launch_bounds__(256) void k_prep(
    const float* __restrict__ qkv_w, const float* __restrict__ w1,
    const float* __restrict__ w2, const float* __restrict__ pw,
    ushort* __restrict__ qkvT, ushort* __restrict__ w1T,
    uchar* __restrict__ w2T8, ushort* __restrict__ projT) {
  int i = blockIdx.x * 256 + threadIdx.x;
  if (i < 49152) {
    int n = i >> 7, k = i & 127;
    qkvT[i] = f2bf(qkv_w[k * 384 + n]);
  } else if (i < 114688) {
    int j = i - 49152;
    int n = j >> 7, k = j & 127;
    w1T[j] = f2bf(w1[k * 512 + n]);
  } else if (i < 147456) {
    int j = i - 114688;            // 32768 k-pairs
    int n = j >> 8, k2 = (j & 255) << 1;
    int u = __builtin_amdgcn_cvt_pk_fp8_f32(w2[(size_t)k2 * 128 + n],
                                            w2[(size_t)(k2 + 1) * 128 + n], 0,
                                            false);
    w2T8[n * 512 + k2] = (uchar)u;
    w2T8[n * 512 + k2 + 1] = (uchar)(u >> 8);
  } else if (i < 163840) {
    int j = i - 147456;
    int n = j >> 7, k = j & 127;
    projT[j] = f2bf(pw[k * 128 + n]);
  }
}

// ---------------------------------------------------------------------------
// K0b: precompute bias+mask table TB[type(4)][head(4)][j(64)][i(64)] f32.
// ---------------------------------------------------------------------------
__global__ __launch_bounds__(256) void k_prep2(
    const float* __restrict__ rpb, float* __restrict__ TB) {
  int e = blockIdx.x * 256 + threadIdx.x;  // < 65536
  int i = e & 63, j = (e >> 6) & 63, h = (e >> 12) & 3, type = e >> 14;
  float v = 0.f;
  if (i < 49 && j < 49) {
    int ri = i / 7, ci = i - ri * 7, rj = j / 7, cj = j - rj * 7;
    int ridx = (ri - rj + 6) * 13 + (ci - cj + 6);
    float bias = rpb[ridx * 4 + h];
    int th = type >> 1, tw = type & 1;
    int labi = (th ? ((ri < 4) ? 1 : 2) : 0) * 3 + (tw ? ((ci < 4) ? 1 : 2) : 0);
    int labj = (th ? ((rj < 4) ? 1 : 2) : 0) * 3 + (tw ? ((cj < 4) ? 1 : 2) : 0);
    v = bias + ((labi != labj) ? -100.f : 0.f);
  }
  TB[e] = v;
}

// ---------------------------------------------------------------------------
// K1: LN(norm1) + cyclic shift(-3,-3) + window partition -> bf16
// ---------------------------------------------------------------------------
__global__ __launch_bounds__(256) void k_ln1_part(
    const float* __restrict__ x, const float* __restrict__ g,
    const float* __restrict__ b, ushort* __restrict__ wp) {
  int lane = threadIdx.x & 63, wv = threadIdx.x >> 6;
  int half = lane >> 5, l32 = lane & 31;
  int tok = blockIdx.x * 8 + wv * 2 + half;    // 0..100351
  size_t src = (size_t)map_row(tok) * 128;
  float4 v = *(const float4*)(x + src + l32 * 4);
  float s = v.x + v.y + v.z + v.w;
  float sq = v.x * v.x + v.y * v.y + v.z * v.z + v.w * v.w;
#pragma unroll
  for (int off = 1; off < 32; off <<= 1) {
    s += __shfl_xor(s, off);
    sq += __shfl_xor(sq, off);
  }
  float mu = s * kInvC;
  float var = sq * kInvC - mu * mu;
  float rs = rsqrtf(var + kEps);
  float4 gg = *(const float4*)(g + l32 * 4);
  float4 bv = *(const float4*)(b + l32 * 4);
  float o0 = (v.x - mu) * rs * gg.x + bv.x;
  float o1 = (v.y - mu) * rs * gg.y + bv.y;
  float o2 = (v.z - mu) * rs * gg.z + bv.z;
  float o3 = (v.w - mu) * rs * gg.w + bv.w;
  uint2 p;
  p.x = (uint)f2bf(o0) | ((uint)f2bf(o1) << 16);
  p.y = (uint)f2bf(o2) | ((uint)f2bf(o3) << 16);
  ((uint2*)wp)[(size_t)tok * 32 + l32] = p;
}

// ---------------------------------------------------------------------------
// K-GEMM2 (M=64 tile): C[64, 128-chunk] = A[M,K] @ BT[N,K]^T + bias (bf16).
// Padded Cs stride (136 ushorts) -> conflict-free epilogue writes.
// ---------------------------------------------------------------------------
template <int K, int LDC, int EPI>
__global__ __launch_bounds__(256) void k_gemm2(
    const ushort* __restrict__ A, const ushort* __restrict__ BT,
    const float* __restrict__ bias, ushort* __restrict__ C) {
  __shared__ ushort sbuf[12288];  // A 4096 | B 8192 (ushorts)
  int tid = threadIdx.x;
  int nBase = blockIdx.x << 7;
  int mBase = blockIdx.y << 6;
  int lane = tid & 63, wid = tid >> 6;
  int li = lane & 15, g = lane >> 4;
  int wr = (wid >> 1) << 5, wc = (wid & 1) << 6;
  int swz = (li & 7) << 3;
  f32x4 acc[2][4] = {};
  for (int ks = 0; ks < K; ks += 64) {
#pragma unroll
    for (int l = 0; l < 2; ++l) {
      int c = l * 256 + tid;
      int row = c >> 3;
      int k8 = ((c & 7) ^ (row & 7)) << 3;
      gl16(A + (size_t)(mBase + row) * K + ks + k8,
           sbuf + (l * 256 + wid * 64) * 8);
    }
#pragma unroll
    for (int l = 0; l < 4; ++l) {
      int c = l * 256 + tid;
      int row = c >> 3;
      int k8 = ((c & 7) ^ (row & 7)) << 3;
      gl16(BT + (size_t)(nBase + row) * K + ks + k8,
           sbuf + 4096 + (l * 256 + wid * 64) * 8);
    }
    __syncthreads();
#pragma unroll
    for (int ksub = 0; ksub < 64; ksub += 32) {
      int kloc = ksub + g * 8;
      bf16x8 af[2], bfr[4];
#pragma unroll
      for (int m = 0; m < 2; ++m)
        af[m] = *(const bf16x8*)(sbuf + (wr + m * 16 + li) * 64 + (kloc ^ swz));
#pragma unroll
      for (int n = 0; n < 4; ++n)
        bfr[n] = *(const bf16x8*)(sbuf + 4096 + (wc + n * 16 + li) * 64 +
                                  (kloc ^ swz));
#pragma unroll
      for (int m = 0; m < 2; ++m)
#pragma unroll
        for (int n = 0; n < 4; ++n)
          acc[m][n] = __builtin_amdgcn_mfma_f32_16x16x32_bf16(
              af[m], bfr[n], acc[m][n], 0, 0, 0);
    }
    __syncthreads();
  }
  // Cs: 64 rows x 128 cols, row stride 136 ushorts (17.4KB overlay)
#pragma unroll
  for (int n = 0; n < 4; ++n) {
    float bv = bias[nBase + wc + n * 16 + li];
    int col = wc + n * 16 + li;
#pragma unroll
    for (int m = 0; m < 2; ++m) {
      int rb = wr + m * 16 + (g << 2);
#pragma unroll
      for (int r = 0; r < 4; ++r) {
        float v = acc[m][n][r] + bv;
        if (EPI == 1) v = gelu_fast(v);
        sbuf[(rb + r) * 136 + col] = f2bf(v);
      }
    }
  }
  __syncthreads();
#pragma unroll
  for (int it = 0; it < 4; ++it) {
    int ch = tid + it * 256;  // 1024 chunks of 8
    int row = ch >> 4, c8 = (ch & 15) << 3;
    *(bf16x8*)(C + (size_t)(mBase + row) * LDC + nBase + c8) =
        *(const bf16x8*)(sbuf + row * 136 + c8);
  }
}

// ---------------------------------------------------------------------------
// K-MLP1 (M=64 tile): hb8[64, 128-chunk] = fp8(gelu_sig(wp@w1T^T + b1)).
// Padded Cs8 stride (144 B) -> conflict-free byte writes.
// ---------------------------------------------------------------------------
__global__ __launch_bounds__(256) void k_mlp1(
    const ushort* __restrict__ A, const ushort* __restrict__ BT,
    const float* __restrict__ bias, uchar* __restrict__ C8) {
  __shared__ ushort sbuf[12288];
  int tid = threadIdx.x;
  int nBase = blockIdx.x << 7;
  int mBase = blockIdx.y << 6;
  int lane = tid & 63, wid = tid >> 6;
  int li = lane & 15, g = lane >> 4;
  int wr = (wid >> 1) << 5, wc = (wid & 1) << 6;
  int swz = (li & 7) << 3;
  f32x4 acc[2][4] = {};
  for (int ks = 0; ks < 128; ks += 64) {
#pragma unroll
    for (int l = 0; l < 2; ++l) {
      int c = l * 256 + tid;
      int row = c >> 3;
      int k8 = ((c & 7) ^ (row & 7)) << 3;
      gl16(A + (size_t)(mBase + row) * 128 + ks + k8,
           sbuf + (l * 256 + wid * 64) * 8);
    }
#pragma unroll
    for (int l = 0; l < 4; ++l) {
      int c = l * 256 + tid;
      int row = c >> 3;
      int k8 = ((c & 7) ^ (row & 7)) << 3;
      gl16(BT + (size_t)(nBase + row) * 128 + ks + k8,
           sbuf + 4096 + (l * 256 + wid * 64) * 8);
    }
    __syncthreads();
#pragma unroll
    for (int ksub = 0; ksub < 64; ksub += 32) {
      int kloc = ksub + g * 8;
      bf16x8 af[2], bfr[4];
#pragma unroll
      for (int m = 0; m < 2; ++m)
        af[m] = *(const bf16x8*)(sbuf + (wr + m * 16 + li) * 64 + (kloc ^ swz));
#pragma unroll
      for (int n = 0; n < 4; ++n)
        bfr[n] = *(const bf16x8*)(sbuf + 4096 + (wc + n * 16 + li) * 64 +
                                  (kloc ^ swz));
#pragma unroll
      for (int m = 0; m < 2; ++m)
#pragma unroll
        for (int n = 0; n < 4; ++n)
          acc[m][n] = __builtin_amdgcn_mfma_f32_16x16x32_bf16(
              af[m], bfr[n], acc[m][n], 0, 0, 0);
    }
    __syncthreads();
  }
  // Cs8: 64 rows x 128 B, row stride 144 B (9.2KB overlay)
  uchar* Cs8 = (uchar*)sbuf;
#pragma unroll
  for (int n = 0; n < 4; ++n) {
    float bv = bias[nBase + wc + n * 16 + li];
    int col = wc + n * 16 + li;
#pragma unroll
    for (int m = 0; m < 2; ++m) {
      int rb = wr + m * 16 + (g << 2);
      float v0 = gelu_sig(acc[m][n][0] + bv);
      float v1 = gelu_sig(acc[m][n][1] + bv);
      float v2 = gelu_sig(acc[m][n][2] + bv);
      float v3 = gelu_sig(acc[m][n][3] + bv);
      int u01 = __builtin_amdgcn_cvt_pk_fp8_f32(v0, v1, 0, false);
      int u23 = __builtin_amdgcn_cvt_pk_fp8_f32(v2, v3, 0, false);
      Cs8[(rb + 0) * 144 + col] = (uchar)u01;
      Cs8[(rb + 1) * 144 + col] = (uchar)(u01 >> 8);
      Cs8[(rb + 2) * 144 + col] = (uchar)u23;
      Cs8[(rb + 3) * 144 + col] = (uchar)(u23 >> 8);
    }
  }
  __syncthreads();
#pragma unroll
  for (int it = 0; it < 2; ++it) {
    int ch = tid + it * 256;  // 512 chunks of 16B
    int row = ch >> 3, c16 = (ch & 7) << 4;
    *(bf16x8*)(C8 + (size_t)(mBase + row) * 512 + nBase + c16) =
        *(const bf16x8*)(Cs8 + row * 144 + c16);
  }
}

// ---------------------------------------------------------------------------
// K-MLP2 (M=64 tile, fp8): out[map(row)] = res_w + hb8 @ w2T8^T + b2.
// ---------------------------------------------------------------------------
__global__ __launch_bounds__(256) void k_mlp2(
    const uchar* __restrict__ A8, const uchar* __restrict__ BT8,
    const float* __restrict__ bias, const ushort* __restrict__ resw,
    float* __restrict__ out) {
  __shared__ uchar sbuf[32768];  // tiles: A 8KB | B 16KB; then f32 out 32KB
  __shared__ int mapr[64];
  int tid = threadIdx.x;
  int mBase = blockIdx.x << 6;
  if (tid < 64) mapr[tid] = map_row(mBase + tid);
  int lane = tid & 63, wid = tid >> 6;
  int li = lane & 15, g = lane >> 4;
  int wr = (wid >> 1) << 5, wc = (wid & 1) << 6;
  f32x4 acc[2][4] = {};
  for (int kb = 0; kb < 512; kb += 128) {
#pragma unroll
    for (int l = 0; l < 2; ++l) {  // A: 64 rows x 128B
      int c = l * 256 + tid;
      int row = c >> 3;
      int ch = (c & 7) ^ (row & 7);
      gl16(A8 + (size_t)(mBase + row) * 512 + kb + (ch << 4),
           sbuf + (l * 256 + wid * 64) * 16);
    }
#pragma unroll
    for (int l = 0; l < 4; ++l) {  // B: 128 rows x 128B
      int c = l * 256 + tid;
      int row = c >> 3;
      int ch = (c & 7) ^ (row & 7);
      gl16(BT8 + (size_t)row * 512 + kb + (ch << 4),
           sbuf + 8192 + (l * 256 + wid * 64) * 16);
    }
    __syncthreads();
#pragma unroll
    for (int ks = 0; ks < 4; ++ks) {
      int off = ks * 32 + g * 8;
      long long af[2], bfr[4];
#pragma unroll
      for (int m = 0; m < 2; ++m) {
        int r = wr + m * 16 + li;
        af[m] = *(const long long*)(sbuf + r * 128 + (off ^ ((r & 7) << 4)));
      }
#pragma unroll
      for (int n = 0; n < 4; ++n) {
        int rb = wc + n * 16 + li;
        bfr[n] = *(const long long*)(sbuf + 8192 + rb * 128 +
                                     (off ^ ((rb & 7) << 4)));
      }
#pragma unroll
      for (int m = 0; m < 2; ++m)
#pragma unroll
        for (int n = 0; n < 4; ++n)
          acc[m][n] = __builtin_amdgcn_mfma_f32_16x16x32_fp8_fp8(
              af[m], bfr[n], acc[m][n], 0, 0, 0);
    }
    __syncthreads();
  }
  float (*outs)[128] = (float(*)[128])sbuf;  // 32 KB f32 overlay
#pragma unroll
  for (int n = 0; n < 4; ++n) {
    int cg = wc + n * 16 + li;
    float bv = bias[cg];
#pragma unroll
    for (int m = 0; m < 2; ++m) {
      int rb = wr + m * 16 + (g << 2);
#pragma unroll
      for (int r = 0; r < 4; ++r) {
        float rv = bf2f(resw[(size_t)(mBase + rb + r) * 128 + cg]);
        outs[rb + r][cg] = rv + acc[m][n][r] + bv;
      }
    }
  }
  __syncthreads();
#pragma unroll
  for (int it = 0; it < 8; ++it) {
    int ch = tid + it * 256;  // 2048 float4 chunks
    int row = ch >> 5, c4 = (ch & 31) << 2;
    *(float4*)(out + (size_t)mapr[row] * 128 + c4) =
        *(const float4*)&outs[row][c4];
  }
}

// ---------------------------------------------------------------------------
// K-PGEMM (M=64 tile): proj GEMM + bias + row-LN(proj_ln) + GELU
//   + residual(x gather) + LN2 -> res_w (bf16) + wp (LN2 bf16).
// ---------------------------------------------------------------------------
__global__ __launch_bounds__(256) void k_pgemm(
    const ushort* __restrict__ A, const ushort* __restrict__ BT,
    const float* __restrict__ pb, const float* __restrict__ lg,
    const float* __restrict__ lb, const float* __restrict__ x,
    const float* __restrict__ g2, const float* __restrict__ b2n,
    ushort* __restrict__ resw, ushort* __restrict__ wp) {
  __shared__ ushort sbuf[16384];  // 32 KB: tiles (24KB), then Cr|Cw overlay
  __shared__ float red[4][64][2];
  __shared__ int mapr[64];
  int tid = threadIdx.x;
  int mBase = blockIdx.x << 6;
  if (tid < 64) mapr[tid] = map_row(mBase + tid);
  int lane = tid & 63, wid = tid >> 6;
  int li = lane & 15, g = lane >> 4;
  int wr = (wid >> 1) << 5, wc = (wid & 1) << 6;
  int swz = (li & 7) << 3;
  f32x4 acc[2][4] = {};
  for (int ks = 0; ks < 128; ks += 64) {
#pragma unroll
    for (int l = 0; l < 2; ++l) {
      int c = l * 256 + tid;
      int row = c >> 3;
      int k8 = ((c & 7) ^ (row & 7)) << 3;
      gl16(A + (size_t)(mBase + row) * 128 + ks + k8,
           sbuf + (l * 256 + wid * 64) * 8);
    }
#pragma unroll
    for (int l = 0; l < 4; ++l) {
      int c = l * 256 + tid;
      int row = c >> 3;
      int k8 = ((c & 7) ^ (row & 7)) << 3;
      gl16(BT + (size_t)row * 128 + ks + k8,
           sbuf + 4096 + (l * 256 + wid * 64) * 8);
    }
    __syncthreads();
#pragma unroll
    for (int ksub = 0; ksub < 64; ksub += 32) {
      int kloc = ksub + g * 8;
      bf16x8 af[2], bfr[4];
#pragma unroll
      for (int m = 0; m < 2; ++m)
        af[m] = *(const bf16x8*)(sbuf + (wr + m * 16 + li) * 64 + (kloc ^ swz));
#pragma unroll
      for (int n = 0; n < 4; ++n)
        bfr[n] = *(const bf16x8*)(sbuf + 4096 + (wc + n * 16 + li) * 64 +
                                  (kloc ^ swz));
#pragma unroll
      for (int m = 0; m < 2; ++m)
#pragma unroll
        for (int n = 0; n < 4; ++n)
          acc[m][n] = __builtin_amdgcn_mfma_f32_16x16x32_bf16(
              af[m], bfr[n], acc[m][n], 0, 0, 0);
    }
    __syncthreads();
  }
  float pbv[4], lgv[4], lbv[4], g2v[4], b2v[4];
#pragma unroll
  for (int n = 0; n < 4; ++n) {
    int cg = wc + n * 16 + li;
    pbv[n] = pb[cg]; lgv[n] = lg[cg]; lbv[n] = lb[cg];
    g2v[n] = g2[cg]; b2v[n] = b2n[cg];
  }
  // pass 1: proj-LN stats (wave covers 64 cols; partner wid^1 has other 64)
  float ps[2][4], psq[2][4];
#pragma unroll
  for (int m = 0; m < 2; ++m)
#pragma unroll
    for (int r = 0; r < 4; ++r) {
      float s = 0.f, q = 0.f;
#pragma unroll
      for (int n = 0; n < 4; ++n) {
        float v = acc[m][n][r] + pbv[n];
        s += v; q += v * v;
      }
#pragma unroll
      for (int off = 1; off < 16; off <<= 1) {
        s += __shfl_xor(s, off);
        q += __shfl_xor(q, off);
      }
      ps[m][r] = s; psq[m][r] = q;
    }
  if (li == 0) {
#pragma unroll
    for (int m = 0; m < 2; ++m)
#pragma unroll
      for (int r = 0; r < 4; ++r) {
        int rl = wr + m * 16 + (g << 2) + r;
        red[wid][rl][0] = ps[m][r];
        red[wid][rl][1] = psq[m][r];
      }
  }
  __syncthreads();
  float mu1[2][4], rs1[2][4];
#pragma unroll
  for (int m = 0; m < 2; ++m)
#pragma unroll
    for (int r = 0; r < 4; ++r) {
      int rl = wr + m * 16 + (g << 2) + r;
      float s = ps[m][r] + red[wid ^ 1][rl][0];
      float q = psq[m][r] + red[wid ^ 1][rl][1];
      mu1[m][r] = s * kInvC;
      rs1[m][r] = rsqrtf(q * kInvC - mu1[m][r] * mu1[m][r] + kEps);
    }
  __syncthreads();  // red free for round 2
  // transform: acc <- res = gelu(projLN(y)) + x[map(row)]
#pragma unroll
  for (int m = 0; m < 2; ++m)
#pragma unroll
    for (int r = 0; r < 4; ++r) {
      int rowl = wr + m * 16 + (g << 2) + r;
      size_t xb = (size_t)mapr[rowl] * 128 + wc + li;
#pragma unroll
      for (int n = 0; n < 4; ++n) {
        float y = (acc[m][n][r] + pbv[n] - mu1[m][r]) * rs1[m][r] * lgv[n] +
                  lbv[n];
        acc[m][n][r] = gelu_fast(y) + x[xb + n * 16];
      }
    }
  // pass 2: LN2 stats on res
#pragma unroll
  for (int m = 0; m < 2; ++m)
#pragma unroll
    for (int r = 0; r < 4; ++r) {
      float s = 0.f, q = 0.f;
#pragma unroll
      for (int n = 0; n < 4; ++n) {
        float v = acc[m][n][r];
        s += v; q += v * v;
      }
#pragma unroll
      for (int off = 1; off < 16; off <<= 1) {
        s += __shfl_xor(s, off);
        q += __shfl_xor(q, off);
      }
      ps[m][r] = s; psq[m][r] = q;
    }
  if (li == 0) {
#pragma unroll
    for (int m = 0; m < 2; ++m)
#pragma unroll
      for (int r = 0; r < 4; ++r) {
        int rl = wr + m * 16 + (g << 2) + r;
        red[wid][rl][0] = ps[m][r];
        red[wid][rl][1] = psq[m][r];
      }
  }
  __syncthreads();
  ushort (*Cr)[128] = (ushort(*)[128])sbuf;            // res bf16 (16KB)
  ushort (*Cw)[128] = (ushort(*)[128])(sbuf + 8192);   // LN2 bf16 (16KB)
#pragma unroll
  for (int m = 0; m < 2; ++m)
#pragma unroll
    for (int r = 0; r < 4; ++r) {
      int rl = wr + m * 16 + (g << 2) + r;
      float s = ps[m][r] + red[wid ^ 1][rl][0];
      float q = psq[m][r] + red[wid ^ 1][rl][1];
      float mu = s * kInvC;
      float rs = rsqrtf(q * kInvC - mu * mu + kEps);
#pragma unroll
      for (int n = 0; n < 4; ++n) {
        int col = wc + n * 16 + li;
        float rv = acc[m][n][r];
        Cr[rl][col] = f2bf(rv);
        Cw[rl][col] = f2bf((rv - mu) * rs * g2v[n] + b2v[n]);
      }
    }
  __syncthreads();
#pragma unroll
  for (int it = 0; it < 4; ++it) {
    int ch = tid + it * 256;  // 1024 chunks of 8
    int row = ch >> 4, c8 = (ch & 15) << 3;
    *(bf16x8*)(resw + (size_t)(mBase + row) * 128 + c8) =
        *(const bf16x8*)&Cr[row][c8];
    *(bf16x8*)(wp + (size_t)(mBase + row) * 128 + c8) =
        *(const bf16x8*)&Cw[row][c8];
  }
}

// ---------------------------------------------------------------------------
// K3: MFMA attention. 1 block = 1 window, 1 wave = 1 head. bf16 P/V.
// Stride-68 LDS (51KB -> 3 blocks/CU); max-free double softmax.
// ---------------------------------------------------------------------------
__global__ __launch_bounds__(256) void k_attn(
    const ushort* __restrict__ qkv, const float* __restrict__ TB,
    ushort* __restrict__ ob) {
  __shared__ ushort Pl[4][64][68];
  __shared__ ushort Vt[4][32][68];
  int tid = threadIdx.x;
  int lane = tid & 63, h = tid >> 6;
  int li = lane & 15, g = lane >> 4;
  int win = blockIdx.x;
  int wi = win & 63;
  int type = (((wi >> 3) == 7) ? 2 : 0) | (((wi & 7) == 7) ? 1 : 0);

  const ushort* qbase = qkv + (size_t)win * 49 * 384 + h * 32 + g * 8;
  bf16x8 kf[4], qf[4];
#pragma unroll
  for (int m = 0; m < 4; ++m) {
    kf[m] = *(const bf16x8*)(qbase + (size_t)(m * 16 + li) * 384 + 128);
    qf[m] = *(const bf16x8*)(qbase + (size_t)(m * 16 + li) * 384);
  }
  f32x4 zero = {0.f, 0.f, 0.f, 0.f};
  f32x4 st[4][4];
#pragma unroll
  for (int m = 0; m < 4; ++m)
#pragma unroll
    for (int n = 0; n < 4; ++n)
      st[m][n] = __builtin_amdgcn_mfma_f32_16x16x32_bf16(kf[m], qf[n], zero, 0, 0, 0);

  if (lane < 49) {
#pragma unroll
    for (int dc = 0; dc < 4; ++dc) {
      bf16x8 vv = *(const bf16x8*)(qkv + ((size_t)win * 49 + lane) * 384 + 256 +
                                   h * 32 + dc * 8);
#pragma unroll
      for (int t = 0; t < 8; ++t) Vt[h][dc * 8 + t][lane] = (ushort)vv[t];
    }
  } else {
#pragma unroll
    for (int d = 0; d < 32; ++d) Vt[h][d][lane] = 0;
  }

  const float* tb = TB + ((size_t)(type * 4 + h) << 12);
#pragma unroll
  for (int n = 0; n < 4; ++n) {
    int icol = n * 16 + li;
    float sv[3][4];
#pragma unroll
    for (int m = 0; m < 3; ++m)
#pragma unroll
      for (int r = 0; r < 4; ++r)
        sv[m][r] = st[m][n][r] * kScale + tb[(m * 16 + g * 4 + r) * 64 + icol];
    float sv3 = (g == 0) ? (st[3][n][0] * kScale + tb[48 * 64 + icol]) : -1e30f;
    // softmax pass 1 (max-free: scores bounded; mask exp underflows to 0)
    float e[3][4], e3 = __expf(sv3);
    float sum = e3;
#pragma unroll
    for (int m = 0; m < 3; ++m)
#pragma unroll
      for (int r = 0; r < 4; ++r) { e[m][r] = __expf(sv[m][r]); sum += e[m][r]; }
    sum += __shfl_xor(sum, 16);
    sum += __shfl_xor(sum, 32);
    float inv = 1.f / sum;
    // softmax pass 2 (inputs in [0,1]; max-free)
    float e2[3][4];
    float e23 = (g == 0) ? __expf(e3 * inv) : 0.f;
    float sum2 = e23;
#pragma unroll
    for (int m = 0; m < 3; ++m)
#pragma unroll
      for (int r = 0; r < 4; ++r) { e2[m][r] = __expf(e[m][r] * inv); sum2 += e2[m][r]; }
    sum2 += __shfl_xor(sum2, 16);
    sum2 += __shfl_xor(sum2, 32);
    float inv2 = 1.f / sum2;
#pragma unroll
    for (int m = 0; m < 3; ++m) {
      uint u0 = (uint)f2bf(e2[m][0] * inv2) | ((uint)f2bf(e2[m][1] * inv2) << 16);
      uint u1 = (uint)f2bf(e2[m][2] * inv2) | ((uint)f2bf(e2[m][3] * inv2) << 16);
      *(uint*)&Pl[h][icol][m * 16 + g * 4]     = u0;
      *(uint*)&Pl[h][icol][m * 16 + g * 4 + 2] = u1;
    }
    uint u3 = (g == 0) ? (uint)f2bf(e23 * inv2) : 0u;
    *(uint*)&Pl[h][icol][48 + g * 4]     = u3;
    *(uint*)&Pl[h][icol][48 + g * 4 + 2] = 0u;
  }
  __syncthreads();

  f32x4 oacc[4][2] = {};
#pragma unroll
  for (int ks = 0; ks < 2; ++ks) {
    int kloc = ks * 32 + g * 8;
    bf16x8 bf0 = *(const bf16x8*)&Vt[h][li][kloc];
    bf16x8 bf1 = *(const bf16x8*)&Vt[h][16 + li][kloc];
#pragma unroll
    for (int mi = 0; mi < 4; ++mi) {
      bf16x8 af = *(const bf16x8*)&Pl[h][mi * 16 + li][kloc];
      oacc[mi][0] = __builtin_amdgcn_mfma_f32_16x16x32_bf16(af, bf0, oacc[mi][0], 0, 0, 0);
      oacc[mi][1] = __builtin_amdgcn_mfma_f32_16x16x32_bf16(af, bf1, oacc[mi][1], 0, 0, 0);
    }
  }
  // stage O (49 x 32 per head) into Pl[h] (stride 40), then wide stores
  ushort* OlH = &Pl[h][0][0];
#pragma unroll
  for (int mi = 0; mi < 4; ++mi)
#pragma unroll
    for (int r = 0; r < 4; ++r) {
      int i = mi * 16 + g * 4 + r;
      if (mi < 3 || (g == 0 && r == 0)) {
        OlH[i * 40 + li]      = f2bf(oacc[mi][0][r]);
        OlH[i * 40 + 16 + li] = f2bf(oacc[mi][1][r]);
      }
    }
  __syncthreads();
  ushort* obase = ob + (size_t)win * 49 * 128;
#pragma unroll
  for (int it = 0; it < 4; ++it) {
    int chunk = tid + it * 256;  // 784 chunks of 8 ushorts
    if (chunk < 784) {
      int row = chunk >> 4, c8 = (chunk & 15) << 3;
      int h2 = c8 >> 5, d8 = c8 & 31;
      bf16x8 v = *(const bf16x8*)(&Pl[h2][0][0] + row * 40 + d8);
      *(bf16x8*)(obase + (size_t)row * 128 + c8) = v;
    }
  }
}

extern "C" void kernel_launch(void* const* d_in, const int* in_sizes, int n_in,
                              void* d_out, int out_size, void* d_ws,
                              size_t ws_size, hipStream_t stream) {
  (void)in_sizes; (void)n_in; (void)out_size; (void)ws_size;
  const float* x      = (const float*)d_in[0];
  const float* qkv_w  = (const float*)d_in[1];
  const float* qkv_b  = (const float*)d_in[2];
  const float* proj_w = (const float*)d_in[3];
  const float* proj_b = (const float*)d_in[4];
  const float* plg    = (const float*)d_in[5];
  const float* plb    = (const float*)d_in[6];
  const float* rpb    = (const float*)d_in[7];
  const float* n1g    = (const float*)d_in[8];
  const float* n1b    = (const float*)d_in[9];
  const float* n2g    = (const float*)d_in[10];
  const float* n2b    = (const float*)d_in[11];
  const float* w1     = (const float*)d_in[12];
  const float* b1     = (const float*)d_in[13];
  const float* w2     = (const float*)d_in[14];
  const float* b2     = (const float*)d_in[15];
  float* out = (float*)d_out;

  // ws layout, ~180 MB
  ushort* wp   = (ushort*)d_ws;                         // 100352*128 bf16
  ushort* qkvb = wp + (size_t)100352 * 128;             // 100352*384 bf16
  ushort* obb  = qkvb + (size_t)100352 * 384;           // 100352*128 bf16
  uchar*  hb8  = (uchar*)(obb + (size_t)100352 * 128);  // 100352*512 fp8
  ushort* qkvT = (ushort*)(hb8 + (size_t)100352 * 512); // 384*128 bf16
  ushort* w1T  = qkvT + 384 * 128;                      // 512*128 bf16
  uchar*  w2T8 = (uchar*)(w1T + 512 * 128);             // 128*512 fp8
  ushort* pT   = (ushort*)(w2T8 + 128 * 512);           // 128*128 bf16
  float*  TB   = (float*)(pT + 128 * 128);              // 4*4*64*64 f32
  ushort* resw = qkvb;  // alias: qkvb dead after k_attn

  k_prep<<<640, 256, 0, stream>>>(qkv_w, w1, w2, proj_w, qkvT, w1T, w2T8, pT);
  k_prep2<<<256, 256, 0, stream>>>(rpb, TB);
  k_ln1_part<<<12544, 256, 0, stream>>>(x, n1g, n1b, wp);
  k_gemm2<128, 384, 0><<<dim3(3, 1568), 256, 0, stream>>>(wp, qkvT, qkv_b, qkvb);
  k_attn<<<2048, 256, 0, stream>>>(qkvb, TB, obb);
  k_pgemm<<<1568, 256, 0, stream>>>(obb, pT, proj_b, plg, plb, x, n2g, n2b,
                                    resw, wp);
  k_mlp1<<<dim3(4, 1568), 256, 0, stream>>>(wp, w1T, b1, hb8);
  k_mlp2<<<1568, 256, 0, stream>>>(hb8, w2T8, b2, resw, out);
}

// Round 22
// 163.840 us; speedup vs baseline: 1.1456x; 1.0299x over previous
//
#include <hip/hip_runtime.h>
#include <cstdint>
#include <cstddef>

typedef __attribute__((ext_vector_type(8))) short bf16x8;
typedef __attribute__((ext_vector_type(4))) float f32x4;
typedef unsigned char uchar;

namespace {
constexpr float kScale = 0.17677669529663689f; // 32^-0.5
constexpr float kEps = 1e-6f;
constexpr float kInvC = 1.0f / 128.0f;

// tanh-form GELU as v*sigmoid(2u) (exact-form, bf16 paths).
__device__ __forceinline__ float gelu_fast(float v) {
  float t1 = fmaf(0.044715f * v, v, 1.0f);
  float x = v * t1 * -1.5957691216057308f;
  float e = __expf(x);
  return v * __builtin_amdgcn_rcpf(1.0f + e);
}
// sigmoid-form GELU v*sigma(1.702v): |err|<=0.003 for |v|<1 — below fp8 noise.
__device__ __forceinline__ float gelu_sig(float v) {
  float e = __expf(-1.702f * v);
  return v * __builtin_amdgcn_rcpf(1.0f + e);
}
__device__ __forceinline__ ushort f2bf(float f) {
  uint32_t u = __builtin_bit_cast(uint32_t, f);
  u += 0x7FFFu + ((u >> 16) & 1u);
  return (ushort)(u >> 16);
}
__device__ __forceinline__ float bf2f(ushort u) {
  return __builtin_bit_cast(float, (uint32_t)u << 16);
}
// async global->LDS, 16B per lane. LDS dest is wave-uniform base + lane*16.
__device__ __forceinline__ void gl16(const void* g, void* l) {
  __builtin_amdgcn_global_load_lds(
      (const __attribute__((address_space(1))) void*)g,
      (__attribute__((address_space(3))) void*)l, 16, 0, 0);
}
// window-token -> natural-token row map (reverse shift + reverse partition)
__device__ __forceinline__ int map_row(int t) {
  int win = t / 49, nn = t - win * 49;
  int bb = win >> 6, wi = win & 63;
  int whi = wi >> 3, wwi = wi & 7;
  int r7 = nn / 7, c7 = nn - r7 * 7;
  int hs = whi * 7 + r7 + 3; if (hs >= 56) hs -= 56;
  int wsd = wwi * 7 + c7 + 3; if (wsd >= 56) wsd -= 56;
  return bb * 3136 + hs * 56 + wsd;
}
} // namespace

// ---------------------------------------------------------------------------
// K0: convert weights: qkvT/w1T bf16 [N][K]; w2T8 fp8 [128][512]; projT bf16.
// ---------------------------------------------------------------------------
__global__ __launch_bounds__(256) void k_prep(
    const float* __restrict__ qkv_w, const float* __restrict__ w1,
    const float* __restrict__ w2, const float* __restrict__ pw,
    ushort* __restrict__ qkvT, ushort* __restrict__ w1T,
    uchar* __restrict__ w2T8, ushort* __restrict__ projT) {
  int i = blockIdx.x * 256 + threadIdx.x;
  if (i < 49152) {
    int n = i >> 7, k = i & 127;
    qkvT[i] = f2bf(qkv_w[k * 384 + n]);
  } else if (i < 114688) {
    int j = i - 49152;
    int n = j >> 7, k = j & 127;
    w1T[j] = f2bf(w1[k * 512 + n]);
  } else if (i < 147456) {
    int j = i - 114688;            // 32768 k-pairs
    int n = j >> 8, k2 = (j & 255) << 1;
    int u = __builtin_amdgcn_cvt_pk_fp8_f32(w2[(size_t)k2 * 128 + n],
                                            w2[(size_t)(k2 + 1) * 128 + n], 0,
                                            false);
    w2T8[n * 512 + k2] = (uchar)u;
    w2T8[n * 512 + k2 + 1] = (uchar)(u >> 8);
  } else if (i < 163840) {
    int j = i - 147456;
    int n = j >> 7, k = j & 127;
    projT[j] = f2bf(pw[k * 128 + n]);
  }
}

// ---------------------------------------------------------------------------
// K0b: precompute bias+mask table TB[type(4)][head(4)][j(64)][i(64)] f32.
// ---------------------------------------------------------------------------
__global__ __launch_bounds__(256) void k_prep2(
    const float* __restrict__ rpb, float* __restrict__ TB) {
  int e = blockIdx.x * 256 + threadIdx.x;  // < 65536
  int i = e & 63, j = (e >> 6) & 63, h = (e >> 12) & 3, type = e >> 14;
  float v = 0.f;
  if (i < 49 && j < 49) {
    int ri = i / 7, ci = i - ri * 7, rj = j / 7, cj = j - rj * 7;
    int ridx = (ri - rj + 6) * 13 + (ci - cj + 6);
    float bias = rpb[ridx * 4 + h];
    int th = type >> 1, tw = type & 1;
    int labi = (th ? ((ri < 4) ? 1 : 2) : 0) * 3 + (tw ? ((ci < 4) ? 1 : 2) : 0);
    int labj = (th ? ((rj < 4) ? 1 : 2) : 0) * 3 + (tw ? ((cj < 4) ? 1 : 2) : 0);
    v = bias + ((labi != labj) ? -100.f : 0.f);
  }
  TB[e] = v;
}

// ---------------------------------------------------------------------------
// K1: LN(norm1) + cyclic shift(-3,-3) + window partition -> bf16
// ---------------------------------------------------------------------------
__global__ __launch_bounds__(256) void k_ln1_part(
    const float* __restrict__ x, const float* __restrict__ g,
    const float* __restrict__ b, ushort* __restrict__ wp) {
  int lane = threadIdx.x & 63, wv = threadIdx.x >> 6;
  int half = lane >> 5, l32 = lane & 31;
  int tok = blockIdx.x * 8 + wv * 2 + half;    // 0..100351
  size_t src = (size_t)map_row(tok) * 128;
  float4 v = *(const float4*)(x + src + l32 * 4);
  float s = v.x + v.y + v.z + v.w;
  float sq = v.x * v.x + v.y * v.y + v.z * v.z + v.w * v.w;
#pragma unroll
  for (int off = 1; off < 32; off <<= 1) {
    s += __shfl_xor(s, off);
    sq += __shfl_xor(sq, off);
  }
  float mu = s * kInvC;
  float var = sq * kInvC - mu * mu;
  float rs = rsqrtf(var + kEps);
  float4 gg = *(const float4*)(g + l32 * 4);
  float4 bv = *(const float4*)(b + l32 * 4);
  float o0 = (v.x - mu) * rs * gg.x + bv.x;
  float o1 = (v.y - mu) * rs * gg.y + bv.y;
  float o2 = (v.z - mu) * rs * gg.z + bv.z;
  float o3 = (v.w - mu) * rs * gg.w + bv.w;
  uint2 p;
  p.x = (uint)f2bf(o0) | ((uint)f2bf(o1) << 16);
  p.y = (uint)f2bf(o2) | ((uint)f2bf(o3) << 16);
  ((uint2*)wp)[(size_t)tok * 32 + l32] = p;
}

// ---------------------------------------------------------------------------
// K-GEMM2 (M=64 tile): C[64, 128-chunk] = A[M,K] @ BT[N,K]^T + bias (bf16).
// XCD-chunked block swizzle: A-sharing blocks land on the same XCD L2.
// ---------------------------------------------------------------------------
template <int K, int LDC, int EPI>
__global__ __launch_bounds__(256) void k_gemm2(
    const ushort* __restrict__ A, const ushort* __restrict__ BT,
    const float* __restrict__ bias, ushort* __restrict__ C) {
  __shared__ ushort sbuf[12288];  // A 4096 | B 8192 (ushorts)
  int tid = threadIdx.x;
  constexpr int NC = LDC / 128;
  int wg = blockIdx.x + NC * blockIdx.y;
  int nwg = NC * (int)gridDim.y;
  int sid = (wg & 7) * (nwg >> 3) + (wg >> 3);
  int nBase = (sid % NC) << 7;
  int mBase = (sid / NC) << 6;
  int lane = tid & 63, wid = tid >> 6;
  int li = lane & 15, g = lane >> 4;
  int wr = (wid >> 1) << 5, wc = (wid & 1) << 6;
  int swz = (li & 7) << 3;
  f32x4 acc[2][4] = {};
  for (int ks = 0; ks < K; ks += 64) {
#pragma unroll
    for (int l = 0; l < 2; ++l) {
      int c = l * 256 + tid;
      int row = c >> 3;
      int k8 = ((c & 7) ^ (row & 7)) << 3;
      gl16(A + (size_t)(mBase + row) * K + ks + k8,
           sbuf + (l * 256 + wid * 64) * 8);
    }
#pragma unroll
    for (int l = 0; l < 4; ++l) {
      int c = l * 256 + tid;
      int row = c >> 3;
      int k8 = ((c & 7) ^ (row & 7)) << 3;
      gl16(BT + (size_t)(nBase + row) * K + ks + k8,
           sbuf + 4096 + (l * 256 + wid * 64) * 8);
    }
    __syncthreads();
#pragma unroll
    for (int ksub = 0; ksub < 64; ksub += 32) {
      int kloc = ksub + g * 8;
      bf16x8 af[2], bfr[4];
#pragma unroll
      for (int m = 0; m < 2; ++m)
        af[m] = *(const bf16x8*)(sbuf + (wr + m * 16 + li) * 64 + (kloc ^ swz));
#pragma unroll
      for (int n = 0; n < 4; ++n)
        bfr[n] = *(const bf16x8*)(sbuf + 4096 + (wc + n * 16 + li) * 64 +
                                  (kloc ^ swz));
#pragma unroll
      for (int m = 0; m < 2; ++m)
#pragma unroll
        for (int n = 0; n < 4; ++n)
          acc[m][n] = __builtin_amdgcn_mfma_f32_16x16x32_bf16(
              af[m], bfr[n], acc[m][n], 0, 0, 0);
    }
    __syncthreads();
  }
  // Cs: 64 rows x 128 cols, row stride 136 ushorts (17.4KB overlay)
#pragma unroll
  for (int n = 0; n < 4; ++n) {
    float bv = bias[nBase + wc + n * 16 + li];
    int col = wc + n * 16 + li;
#pragma unroll
    for (int m = 0; m < 2; ++m) {
      int rb = wr + m * 16 + (g << 2);
#pragma unroll
      for (int r = 0; r < 4; ++r) {
        float v = acc[m][n][r] + bv;
        if (EPI == 1) v = gelu_fast(v);
        sbuf[(rb + r) * 136 + col] = f2bf(v);
      }
    }
  }
  __syncthreads();
#pragma unroll
  for (int it = 0; it < 4; ++it) {
    int ch = tid + it * 256;  // 1024 chunks of 8
    int row = ch >> 4, c8 = (ch & 15) << 3;
    *(bf16x8*)(C + (size_t)(mBase + row) * LDC + nBase + c8) =
        *(const bf16x8*)(sbuf + row * 136 + c8);
  }
}

// ---------------------------------------------------------------------------
// K-MLP1 (M=64 tile): hb8[64, 128-chunk] = fp8(gelu_sig(wp@w1T^T + b1)).
// XCD-chunked block swizzle; padded Cs8 stride (144 B).
// ---------------------------------------------------------------------------
__global__ __launch_bounds__(256) void k_mlp1(
    const ushort* __restrict__ A, const ushort* __restrict__ BT,
    const float* __restrict__ bias, uchar* __restrict__ C8) {
  __shared__ ushort sbuf[12288];
  int tid = threadIdx.x;
  int wg = blockIdx.x + 4 * blockIdx.y;
  int nwg = 4 * (int)gridDim.y;
  int sid = (wg & 7) * (nwg >> 3) + (wg >> 3);
  int nBase = (sid & 3) << 7;
  int mBase = (sid >> 2) << 6;
  int lane = tid & 63, wid = tid >> 6;
  int li = lane & 15, g = lane >> 4;
  int wr = (wid >> 1) << 5, wc = (wid & 1) << 6;
  int swz = (li & 7) << 3;
  f32x4 acc[2][4] = {};
  for (int ks = 0; ks < 128; ks += 64) {
#pragma unroll
    for (int l = 0; l < 2; ++l) {
      int c = l * 256 + tid;
      int row = c >> 3;
      int k8 = ((c & 7) ^ (row & 7)) << 3;
      gl16(A + (size_t)(mBase + row) * 128 + ks + k8,
           sbuf + (l * 256 + wid * 64) * 8);
    }
#pragma unroll
    for (int l = 0; l < 4; ++l) {
      int c = l * 256 + tid;
      int row = c >> 3;
      int k8 = ((c & 7) ^ (row & 7)) << 3;
      gl16(BT + (size_t)(nBase + row) * 128 + ks + k8,
           sbuf + 4096 + (l * 256 + wid * 64) * 8);
    }
    __syncthreads();
#pragma unroll
    for (int ksub = 0; ksub < 64; ksub += 32) {
      int kloc = ksub + g * 8;
      bf16x8 af[2], bfr[4];
#pragma unroll
      for (int m = 0; m < 2; ++m)
        af[m] = *(const bf16x8*)(sbuf + (wr + m * 16 + li) * 64 + (kloc ^ swz));
#pragma unroll
      for (int n = 0; n < 4; ++n)
        bfr[n] = *(const bf16x8*)(sbuf + 4096 + (wc + n * 16 + li) * 64 +
                                  (kloc ^ swz));
#pragma unroll
      for (int m = 0; m < 2; ++m)
#pragma unroll
        for (int n = 0; n < 4; ++n)
          acc[m][n] = __builtin_amdgcn_mfma_f32_16x16x32_bf16(
              af[m], bfr[n], acc[m][n], 0, 0, 0);
    }
    __syncthreads();
  }
  // Cs8: 64 rows x 128 B, row stride 144 B (9.2KB overlay)
  uchar* Cs8 = (uchar*)sbuf;
#pragma unroll
  for (int n = 0; n < 4; ++n) {
    float bv = bias[nBase + wc + n * 16 + li];
    int col = wc + n * 16 + li;
#pragma unroll
    for (int m = 0; m < 2; ++m) {
      int rb = wr + m * 16 + (g << 2);
      float v0 = gelu_sig(acc[m][n][0] + bv);
      float v1 = gelu_sig(acc[m][n][1] + bv);
      float v2 = gelu_sig(acc[m][n][2] + bv);
      float v3 = gelu_sig(acc[m][n][3] + bv);
      int u01 = __builtin_amdgcn_cvt_pk_fp8_f32(v0, v1, 0, false);
      int u23 = __builtin_amdgcn_cvt_pk_fp8_f32(v2, v3, 0, false);
      Cs8[(rb + 0) * 144 + col] = (uchar)u01;
      Cs8[(rb + 1) * 144 + col] = (uchar)(u01 >> 8);
      Cs8[(rb + 2) * 144 + col] = (uchar)u23;
      Cs8[(rb + 3) * 144 + col] = (uchar)(u23 >> 8);
    }
  }
  __syncthreads();
#pragma unroll
  for (int it = 0; it < 2; ++it) {
    int ch = tid + it * 256;  // 512 chunks of 16B
    int row = ch >> 3, c16 = (ch & 7) << 4;
    *(bf16x8*)(C8 + (size_t)(mBase + row) * 512 + nBase + c16) =
        *(const bf16x8*)(Cs8 + row * 144 + c16);
  }
}

// ---------------------------------------------------------------------------
// K-MLP2 (M=64 tile, fp8): out[map(row)] = res_w + hb8 @ w2T8^T + b2.
// ---------------------------------------------------------------------------
__global__ __launch_bounds__(256) void k_mlp2(
    const uchar* __restrict__ A8, const uchar* __restrict__ BT8,
    const float* __restrict__ bias, const ushort* __restrict__ resw,
    float* __restrict__ out) {
  __shared__ uchar sbuf[32768];  // tiles: A 8KB | B 16KB; then f32 out 32KB
  __shared__ int mapr[64];
  int tid = threadIdx.x;
  int mBase = blockIdx.x << 6;
  if (tid < 64) mapr[tid] = map_row(mBase + tid);
  int lane = tid & 63, wid = tid >> 6;
  int li = lane & 15, g = lane >> 4;
  int wr = (wid >> 1) << 5, wc = (wid & 1) << 6;
  f32x4 acc[2][4] = {};
  for (int kb = 0; kb < 512; kb += 128) {
#pragma unroll
    for (int l = 0; l < 2; ++l) {  // A: 64 rows x 128B
      int c = l * 256 + tid;
      int row = c >> 3;
      int ch = (c & 7) ^ (row & 7);
      gl16(A8 + (size_t)(mBase + row) * 512 + kb + (ch << 4),
           sbuf + (l * 256 + wid * 64) * 16);
    }
#pragma unroll
    for (int l = 0; l < 4; ++l) {  // B: 128 rows x 128B
      int c = l * 256 + tid;
      int row = c >> 3;
      int ch = (c & 7) ^ (row & 7);
      gl16(BT8 + (size_t)row * 512 + kb + (ch << 4),
           sbuf + 8192 + (l * 256 + wid * 64) * 16);
    }
    __syncthreads();
#pragma unroll
    for (int ks = 0; ks < 4; ++ks) {
      int off = ks * 32 + g * 8;
      long long af[2], bfr[4];
#pragma unroll
      for (int m = 0; m < 2; ++m) {
        int r = wr + m * 16 + li;
        af[m] = *(const long long*)(sbuf + r * 128 + (off ^ ((r & 7) << 4)));
      }
#pragma unroll
      for (int n = 0; n < 4; ++n) {
        int rb = wc + n * 16 + li;
        bfr[n] = *(const long long*)(sbuf + 8192 + rb * 128 +
                                     (off ^ ((rb & 7) << 4)));
      }
#pragma unroll
      for (int m = 0; m < 2; ++m)
#pragma unroll
        for (int n = 0; n < 4; ++n)
          acc[m][n] = __builtin_amdgcn_mfma_f32_16x16x32_fp8_fp8(
              af[m], bfr[n], acc[m][n], 0, 0, 0);
    }
    __syncthreads();
  }
  float (*outs)[128] = (float(*)[128])sbuf;  // 32 KB f32 overlay
#pragma unroll
  for (int n = 0; n < 4; ++n) {
    int cg = wc + n * 16 + li;
    float bv = bias[cg];
#pragma unroll
    for (int m = 0; m < 2; ++m) {
      int rb = wr + m * 16 + (g << 2);
#pragma unroll
      for (int r = 0; r < 4; ++r) {
        float rv = bf2f(resw[(size_t)(mBase + rb + r) * 128 + cg]);
        outs[rb + r][cg] = rv + acc[m][n][r] + bv;
      }
    }
  }
  __syncthreads();
#pragma unroll
  for (int it = 0; it < 8; ++it) {
    int ch = tid + it * 256;  // 2048 float4 chunks
    int row = ch >> 5, c4 = (ch & 31) << 2;
    *(float4*)(out + (size_t)mapr[row] * 128 + c4) =
        *(const float4*)&outs[row][c4];
  }
}

// ---------------------------------------------------------------------------
// K-PGEMM (M=64 tile): proj GEMM + bias + row-LN(proj_ln) + GELU
//   + residual(x gather) + LN2 -> res_w (bf16) + wp (LN2 bf16).
// ---------------------------------------------------------------------------
__global__ __launch_bounds__(256) void k_pgemm(
    const ushort* __restrict__ A, const ushort* __restrict__ BT,
    const float* __restrict__ pb, const float* __restrict__ lg,
    const float* __restrict__ lb, const float* __restrict__ x,
    const float* __restrict__ g2, const float* __restrict__ b2n,
    ushort* __restrict__ resw, ushort* __restrict__ wp) {
  __shared__ ushort sbuf[16384];  // 32 KB: tiles (24KB), then Cr|Cw overlay
  __shared__ float red[4][64][2];
  __shared__ int mapr[64];
  int tid = threadIdx.x;
  int mBase = blockIdx.x << 6;
  if (tid < 64) mapr[tid] = map_row(mBase + tid);
  int lane = tid & 63, wid = tid >> 6;
  int li = lane & 15, g = lane >> 4;
  int wr = (wid >> 1) << 5, wc = (wid & 1) << 6;
  int swz = (li & 7) << 3;
  f32x4 acc[2][4] = {};
  for (int ks = 0; ks < 128; ks += 64) {
#pragma unroll
    for (int l = 0; l < 2; ++l) {
      int c = l * 256 + tid;
      int row = c >> 3;
      int k8 = ((c & 7) ^ (row & 7)) << 3;
      gl16(A + (size_t)(mBase + row) * 128 + ks + k8,
           sbuf + (l * 256 + wid * 64) * 8);
    }
#pragma unroll
    for (int l = 0; l < 4; ++l) {
      int c = l * 256 + tid;
      int row = c >> 3;
      int k8 = ((c & 7) ^ (row & 7)) << 3;
      gl16(BT + (size_t)row * 128 + ks + k8,
           sbuf + 4096 + (l * 256 + wid * 64) * 8);
    }
    __syncthreads();
#pragma unroll
    for (int ksub = 0; ksub < 64; ksub += 32) {
      int kloc = ksub + g * 8;
      bf16x8 af[2], bfr[4];
#pragma unroll
      for (int m = 0; m < 2; ++m)
        af[m] = *(const bf16x8*)(sbuf + (wr + m * 16 + li) * 64 + (kloc ^ swz));
#pragma unroll
      for (int n = 0; n < 4; ++n)
        bfr[n] = *(const bf16x8*)(sbuf + 4096 + (wc + n * 16 + li) * 64 +
                                  (kloc ^ swz));
#pragma unroll
      for (int m = 0; m < 2; ++m)
#pragma unroll
        for (int n = 0; n < 4; ++n)
          acc[m][n] = __builtin_amdgcn_mfma_f32_16x16x32_bf16(
              af[m], bfr[n], acc[m][n], 0, 0, 0);
    }
    __syncthreads();
  }
  float pbv[4], lgv[4], lbv[4], g2v[4], b2v[4];
#pragma unroll
  for (int n = 0; n < 4; ++n) {
    int cg = wc + n * 16 + li;
    pbv[n] = pb[cg]; lgv[n] = lg[cg]; lbv[n] = lb[cg];
    g2v[n] = g2[cg]; b2v[n] = b2n[cg];
  }
  // pass 1: proj-LN stats (wave covers 64 cols; partner wid^1 has other 64)
  float ps[2][4], psq[2][4];
#pragma unroll
  for (int m = 0; m < 2; ++m)
#pragma unroll
    for (int r = 0; r < 4; ++r) {
      float s = 0.f, q = 0.f;
#pragma unroll
      for (int n = 0; n < 4; ++n) {
        float v = acc[m][n][r] + pbv[n];
        s += v; q += v * v;
      }
#pragma unroll
      for (int off = 1; off < 16; off <<= 1) {
        s += __shfl_xor(s, off);
        q += __shfl_xor(q, off);
      }
      ps[m][r] = s; psq[m][r] = q;
    }
  if (li == 0) {
#pragma unroll
    for (int m = 0; m < 2; ++m)
#pragma unroll
      for (int r = 0; r < 4; ++r) {
        int rl = wr + m * 16 + (g << 2) + r;
        red[wid][rl][0] = ps[m][r];
        red[wid][rl][1] = psq[m][r];
      }
  }
  __syncthreads();
  float mu1[2][4], rs1[2][4];
#pragma unroll
  for (int m = 0; m < 2; ++m)
#pragma unroll
    for (int r = 0; r < 4; ++r) {
      int rl = wr + m * 16 + (g << 2) + r;
      float s = ps[m][r] + red[wid ^ 1][rl][0];
      float q = psq[m][r] + red[wid ^ 1][rl][1];
      mu1[m][r] = s * kInvC;
      rs1[m][r] = rsqrtf(q * kInvC - mu1[m][r] * mu1[m][r] + kEps);
    }
  __syncthreads();  // red free for round 2
  // transform: acc <- res = gelu(projLN(y)) + x[map(row)]
#pragma unroll
  for (int m = 0; m < 2; ++m)
#pragma unroll
    for (int r = 0; r < 4; ++r) {
      int rowl = wr + m * 16 + (g << 2) + r;
      size_t xb = (size_t)mapr[rowl] * 128 + wc + li;
#pragma unroll
      for (int n = 0; n < 4; ++n) {
        float y = (acc[m][n][r] + pbv[n] - mu1[m][r]) * rs1[m][r] * lgv[n] +
                  lbv[n];
        acc[m][n][r] = gelu_fast(y) + x[xb + n * 16];
      }
    }
  // pass 2: LN2 stats on res
#pragma unroll
  for (int m = 0; m < 2; ++m)
#pragma unroll
    for (int r = 0; r < 4; ++r) {
      float s = 0.f, q = 0.f;
#pragma unroll
      for (int n = 0; n < 4; ++n) {
        float v = acc[m][n][r];
        s += v; q += v * v;
      }
#pragma unroll
      for (int off = 1; off < 16; off <<= 1) {
        s += __shfl_xor(s, off);
        q += __shfl_xor(q, off);
      }
      ps[m][r] = s; psq[m][r] = q;
    }
  if (li == 0) {
#pragma unroll
    for (int m = 0; m < 2; ++m)
#pragma unroll
      for (int r = 0; r < 4; ++r) {
        int rl = wr + m * 16 + (g << 2) + r;
        red[wid][rl][0] = ps[m][r];
        red[wid][rl][1] = psq[m][r];
      }
  }
  __syncthreads();
  ushort (*Cr)[128] = (ushort(*)[128])sbuf;            // res bf16 (16KB)
  ushort (*Cw)[128] = (ushort(*)[128])(sbuf + 8192);   // LN2 bf16 (16KB)
#pragma unroll
  for (int m = 0; m < 2; ++m)
#pragma unroll
    for (int r = 0; r < 4; ++r) {
      int rl = wr + m * 16 + (g << 2) + r;
      float s = ps[m][r] + red[wid ^ 1][rl][0];
      float q = psq[m][r] + red[wid ^ 1][rl][1];
      float mu = s * kInvC;
      float rs = rsqrtf(q * kInvC - mu * mu + kEps);
#pragma unroll
      for (int n = 0; n < 4; ++n) {
        int col = wc + n * 16 + li;
        float rv = acc[m][n][r];
        Cr[rl][col] = f2bf(rv);
        Cw[rl][col] = f2bf((rv - mu) * rs * g2v[n] + b2v[n]);
      }
    }
  __syncthreads();
#pragma unroll
  for (int it = 0; it < 4; ++it) {
    int ch = tid + it * 256;  // 1024 chunks of 8
    int row = ch >> 4, c8 = (ch & 15) << 3;
    *(bf16x8*)(resw + (size_t)(mBase + row) * 128 + c8) =
        *(const bf16x8*)&Cr[row][c8];
    *(bf16x8*)(wp + (size_t)(mBase + row) * 128 + c8) =
        *(const bf16x8*)&Cw[row][c8];
  }
}

// ---------------------------------------------------------------------------
// K3: MFMA attention. 1 block = 1 window, 1 wave = 1 head. bf16 P/V.
// Stride-68 LDS (51KB -> 3 blocks/CU); max-free double softmax.
// ---------------------------------------------------------------------------
__global__ __launch_bounds__(256) void k_attn(
    const ushort* __restrict__ qkv, const float* __restrict__ TB,
    ushort* __restrict__ ob) {
  __shared__ ushort Pl[4][64][68];
  __shared__ ushort Vt[4][32][68];
  int tid = threadIdx.x;
  int lane = tid & 63, h = tid >> 6;
  int li = lane & 15, g = lane >> 4;
  int win = blockIdx.x;
  int wi = win & 63;
  int type = (((wi >> 3) == 7) ? 2 : 0) | (((wi & 7) == 7) ? 1 : 0);

  const ushort* qbase = qkv + (size_t)win * 49 * 384 + h * 32 + g * 8;
  bf16x8 kf[4], qf[4];
#pragma unroll
  for (int m = 0; m < 4; ++m) {
    kf[m] = *(const bf16x8*)(qbase + (size_t)(m * 16 + li) * 384 + 128);
    qf[m] = *(const bf16x8*)(qbase + (size_t)(m * 16 + li) * 384);
  }
  f32x4 zero = {0.f, 0.f, 0.f, 0.f};
  f32x4 st[4][4];
#pragma unroll
  for (int m = 0; m < 4; ++m)
#pragma unroll
    for (int n = 0; n < 4; ++n)
      st[m][n] = __builtin_amdgcn_mfma_f32_16x16x32_bf16(kf[m], qf[n], zero, 0, 0, 0);

  if (lane < 49) {
#pragma unroll
    for (int dc = 0; dc < 4; ++dc) {
      bf16x8 vv = *(const bf16x8*)(qkv + ((size_t)win * 49 + lane) * 384 + 256 +
                                   h * 32 + dc * 8);
#pragma unroll
      for (int t = 0; t < 8; ++t) Vt[h][dc * 8 + t][lane] = (ushort)vv[t];
    }
  } else {
#pragma unroll
    for (int d = 0; d < 32; ++d) Vt[h][d][lane] = 0;
  }

  const float* tb = TB + ((size_t)(type * 4 + h) << 12);
#pragma unroll
  for (int n = 0; n < 4; ++n) {
    int icol = n * 16 + li;
    float sv[3][4];
#pragma unroll
    for (int m = 0; m < 3; ++m)
#pragma unroll
      for (int r = 0; r < 4; ++r)
        sv[m][r] = st[m][n][r] * kScale + tb[(m * 16 + g * 4 + r) * 64 + icol];
    float sv3 = (g == 0) ? (st[3][n][0] * kScale + tb[48 * 64 + icol]) : -1e30f;
    // softmax pass 1 (max-free: scores bounded; mask exp underflows to 0)
    float e[3][4], e3 = __expf(sv3);
    float sum = e3;
#pragma unroll
    for (int m = 0; m < 3; ++m)
#pragma unroll
      for (int r = 0; r < 4; ++r) { e[m][r] = __expf(sv[m][r]); sum += e[m][r]; }
    sum += __shfl_xor(sum, 16);
    sum += __shfl_xor(sum, 32);
    float inv = 1.f / sum;
    // softmax pass 2 (inputs in [0,1]; max-free)
    float e2[3][4];
    float e23 = (g == 0) ? __expf(e3 * inv) : 0.f;
    float sum2 = e23;
#pragma unroll
    for (int m = 0; m < 3; ++m)
#pragma unroll
      for (int r = 0; r < 4; ++r) { e2[m][r] = __expf(e[m][r] * inv); sum2 += e2[m][r]; }
    sum2 += __shfl_xor(sum2, 16);
    sum2 += __shfl_xor(sum2, 32);
    float inv2 = 1.f / sum2;
#pragma unroll
    for (int m = 0; m < 3; ++m) {
      uint u0 = (uint)f2bf(e2[m][0] * inv2) | ((uint)f2bf(e2[m][1] * inv2) << 16);
      uint u1 = (uint)f2bf(e2[m][2] * inv2) | ((uint)f2bf(e2[m][3] * inv2) << 16);
      *(uint*)&Pl[h][icol][m * 16 + g * 4]     = u0;
      *(uint*)&Pl[h][icol][m * 16 + g * 4 + 2] = u1;
    }
    uint u3 = (g == 0) ? (uint)f2bf(e23 * inv2) : 0u;
    *(uint*)&Pl[h][icol][48 + g * 4]     = u3;
    *(uint*)&Pl[h][icol][48 + g * 4 + 2] = 0u;
  }
  __syncthreads();

  f32x4 oacc[4][2] = {};
#pragma unroll
  for (int ks = 0; ks < 2; ++ks) {
    int kloc = ks * 32 + g * 8;
    bf16x8 bf0 = *(const bf16x8*)&Vt[h][li][kloc];
    bf16x8 bf1 = *(const bf16x8*)&Vt[h][16 + li][kloc];
#pragma unroll
    for (int mi = 0; mi < 4; ++mi) {
      bf16x8 af = *(const bf16x8*)&Pl[h][mi * 16 + li][kloc];
      oacc[mi][0] = __builtin_amdgcn_mfma_f32_16x16x32_bf16(af, bf0, oacc[mi][0], 0, 0, 0);
      oacc[mi][1] = __builtin_amdgcn_mfma_f32_16x16x32_bf16(af, bf1, oacc[mi][1], 0, 0, 0);
    }
  }
  // stage O (49 x 32 per head) into Pl[h] (stride 40), then wide stores
  ushort* OlH = &Pl[h][0][0];
#pragma unroll
  for (int mi = 0; mi < 4; ++mi)
#pragma unroll
    for (int r = 0; r < 4; ++r) {
      int i = mi * 16 + g * 4 + r;
      if (mi < 3 || (g == 0 && r == 0)) {
        OlH[i * 40 + li]      = f2bf(oacc[mi][0][r]);
        OlH[i * 40 + 16 + li] = f2bf(oacc[mi][1][r]);
      }
    }
  __syncthreads();
  ushort* obase = ob + (size_t)win * 49 * 128;
#pragma unroll
  for (int it = 0; it < 4; ++it) {
    int chunk = tid + it * 256;  // 784 chunks of 8 ushorts
    if (chunk < 784) {
      int row = chunk >> 4, c8 = (chunk & 15) << 3;
      int h2 = c8 >> 5, d8 = c8 & 31;
      bf16x8 v = *(const bf16x8*)(&Pl[h2][0][0] + row * 40 + d8);
      *(bf16x8*)(obase + (size_t)row * 128 + c8) = v;
    }
  }
}

extern "C" void kernel_launch(void* const* d_in, const int* in_sizes, int n_in,
                              void* d_out, int out_size, void* d_ws,
                              size_t ws_size, hipStream_t stream) {
  (void)in_sizes; (void)n_in; (void)out_size; (void)ws_size;
  const float* x      = (const float*)d_in[0];
  const float* qkv_w  = (const float*)d_in[1];
  const float* qkv_b  = (const float*)d_in[2];
  const float* proj_w = (const float*)d_in[3];
  const float* proj_b = (const float*)d_in[4];
  const float* plg    = (const float*)d_in[5];
  const float* plb    = (const float*)d_in[6];
  const float* rpb    = (const float*)d_in[7];
  const float* n1g    = (const float*)d_in[8];
  const float* n1b    = (const float*)d_in[9];
  const float* n2g    = (const float*)d_in[10];
  const float* n2b    = (const float*)d_in[11];
  const float* w1     = (const float*)d_in[12];
  const float* b1     = (const float*)d_in[13];
  const float* w2     = (const float*)d_in[14];
  const float* b2     = (const float*)d_in[15];
  float* out = (float*)d_out;

  // ws layout, ~180 MB
  ushort* wp   = (ushort*)d_ws;                         // 100352*128 bf16
  ushort* qkvb = wp + (size_t)100352 * 128;             // 100352*384 bf16
  ushort* obb  = qkvb + (size_t)100352 * 384;           // 100352*128 bf16
  uchar*  hb8  = (uchar*)(obb + (size_t)100352 * 128);  // 100352*512 fp8
  ushort* qkvT = (ushort*)(hb8 + (size_t)100352 * 512); // 384*128 bf16
  ushort* w1T  = qkvT + 384 * 128;                      // 512*128 bf16
  uchar*  w2T8 = (uchar*)(w1T + 512 * 128);             // 128*512 fp8
  ushort* pT   = (ushort*)(w2T8 + 128 * 512);           // 128*128 bf16
  float*  TB   = (float*)(pT + 128 * 128);              // 4*4*64*64 f32
  ushort* resw = qkvb;  // alias: qkvb dead after k_attn

  k_prep<<<640, 256, 0, stream>>>(qkv_w, w1, w2, proj_w, qkvT, w1T, w2T8, pT);
  k_prep2<<<256, 256, 0, stream>>>(rpb, TB);
  k_ln1_part<<<12544, 256, 0, stream>>>(x, n1g, n1b, wp);
  k_gemm2<128, 384, 0><<<dim3(3, 1568), 256, 0, stream>>>(wp, qkvT, qkv_b, qkvb);
  k_attn<<<2048, 256, 0, stream>>>(qkvb, TB, obb);
  k_pgemm<<<1568, 256, 0, stream>>>(obb, pT, proj_b, plg, plb, x, n2g, n2b,
                                    resw, wp);
  k_mlp1<<<dim3(4, 1568), 256, 0, stream>>>(wp, w1T, b1, hb8);
  k_mlp2<<<1568, 256, 0, stream>>>(hb8, w2T8, b2, resw, out);
}